// Round 1
// baseline (513.509 us; speedup 1.0000x reference)
//
#include <hip/hip_runtime.h>
#include <hip/hip_bf16.h>
#include <math.h>

// Problem constants
#define NB 96        // batch / nodes
#define TT 160       // sequence length
#define DD 96        // feature dim
#define D_STATE 64
#define D_CONV 4
#define HEADDIM 32
#define NGROUPS 6
#define D_INNER 192
#define NHEADS 6
#define EMB 24
#define DOUT 64
#define D_IN_PROJ 1158
#define CONV_DIM 960
#define TN 15360     // TT*DD = input row stride per node, also rows of z
#define BN_EPS 1e-5f
#define RMS_EPS 1e-5f

__device__ __forceinline__ float siluf(float x) { return x / (1.f + expf(-x)); }
__device__ __forceinline__ float softplusf(float x) {
    return fmaxf(x, 0.f) + log1pf(expf(-fabsf(x)));
}

// ---------------------------------------------------------------------------
// K1: per-t aggregation: a-embeddings, s1, s2, gin = xs + agg
// ---------------------------------------------------------------------------
__global__ __launch_bounds__(256) void k1_agg(
    const float* __restrict__ input, const int* __restrict__ hem,
    const int* __restrict__ subnet, const float* __restrict__ hem_emb,
    const float* __restrict__ subnet_emb, float* __restrict__ gin) {
  int t = blockIdx.x;
  __shared__ float xs[96 * 96];
  __shared__ float al[96 * 48];
  __shared__ float s1[48];
  __shared__ float s2[96 * 48];
  int tid = threadIdx.x;

  for (int o = tid; o < 96 * 96; o += 256) {
    int i = o / 96, d = o % 96;
    xs[o] = input[i * TN + t * 96 + d];
  }
  for (int o = tid; o < 96 * 48; o += 256) {
    int i = o / 48, c = o % 48;
    al[o] = (c < 24) ? hem_emb[hem[i] * 24 + c]
                     : subnet_emb[subnet[i] * 24 + (c - 24)];
  }
  __syncthreads();
  if (tid < 48) {
    float s = 0.f;
    for (int i = 0; i < 96; i++) s += fmaxf(xs[i * 96 + tid] + al[i * 48 + tid], 0.f);
    s1[tid] = s;
  }
  for (int o = tid; o < 96 * 48; o += 256) {
    int j = o / 48, c = o % 48;
    float av = al[j * 48 + c];
    float s = 0.f;
    for (int i = 0; i < 96; i++) s += fmaxf(xs[i * 96 + 48 + c] + av, 0.f);
    s2[o] = s;
  }
  __syncthreads();
  for (int o = tid; o < 96 * 96; o += 256) {
    int j = o / 96, d = o % 96;
    float aggv = (d < 48) ? s1[d] : s2[j * 48 + (d - 48)];
    gin[t * 9216 + o] = xs[o] + aggv;
  }
}

// ---------------------------------------------------------------------------
// K2: per-t GINE MLP + residual + node-batchnorm -> z (b-major layout)
// ---------------------------------------------------------------------------
__global__ __launch_bounds__(256) void k2_gine(
    const float* __restrict__ gin, const float* __restrict__ input,
    const float* __restrict__ W1, const float* __restrict__ b1,
    const float* __restrict__ W2, const float* __restrict__ b2,
    const float* __restrict__ bn_w, const float* __restrict__ bn_b,
    float* __restrict__ z) {
  int t = blockIdx.x;
  __shared__ float A[96 * 96];   // gin, later h
  __shared__ float Hd[96 * 96];  // hidden
  __shared__ float Wl[96 * 96];  // weights
  __shared__ float mu[96], rs[96];
  int tid = threadIdx.x;

  for (int o = tid; o < 9216; o += 256) A[o] = gin[t * 9216 + o];
  for (int o = tid; o < 9216; o += 256) Wl[o] = W1[o];
  __syncthreads();
  for (int o = tid; o < 9216; o += 256) {
    int j = o / 96, d = o % 96;
    float acc = b1[d];
    for (int k = 0; k < 96; k++) acc += A[j * 96 + k] * Wl[k * 96 + d];
    Hd[o] = fmaxf(acc, 0.f);
  }
  __syncthreads();
  for (int o = tid; o < 9216; o += 256) Wl[o] = W2[o];
  __syncthreads();
  for (int o = tid; o < 9216; o += 256) {
    int j = o / 96, d = o % 96;
    float acc = b2[d];
    for (int k = 0; k < 96; k++) acc += Hd[j * 96 + k] * Wl[k * 96 + d];
    acc += input[j * TN + t * 96 + d];  // + xs residual
    A[o] = acc;
  }
  __syncthreads();
  if (tid < 96) {
    float m = 0.f;
    for (int j = 0; j < 96; j++) m += A[j * 96 + tid];
    m *= (1.f / 96.f);
    float v = 0.f;
    for (int j = 0; j < 96; j++) { float dd = A[j * 96 + tid] - m; v += dd * dd; }
    v *= (1.f / 96.f);
    mu[tid] = m;
    rs[tid] = rsqrtf(v + BN_EPS);
  }
  __syncthreads();
  for (int o = tid; o < 9216; o += 256) {
    int j = o / 96, d = o % 96;
    float val = (A[o] - mu[d]) * rs[d] * bn_w[d] + bn_b[d];
    z[j * TN + t * 96 + d] = val;  // z[b][l][d]
  }
}

// ---------------------------------------------------------------------------
// K3: in_proj GEMM: (15360 x 96) @ (96 x 1158) -> zxbcdt
// ---------------------------------------------------------------------------
__global__ __launch_bounds__(256) void k3_gemm(
    const float* __restrict__ Z, const float* __restrict__ W,
    float* __restrict__ C) {
  int m0 = blockIdx.x * 64;
  int n0 = blockIdx.y * 64;
  __shared__ float As[64][97];
  __shared__ float Bs[96][64];
  int tid = threadIdx.x;

  for (int o = tid; o < 64 * 96; o += 256) {
    int r = o / 96, k = o % 96;
    As[r][k] = Z[(size_t)(m0 + r) * 96 + k];
  }
  for (int o = tid; o < 96 * 64; o += 256) {
    int k = o / 64, c = o % 64;
    int col = n0 + c;
    Bs[k][c] = (col < D_IN_PROJ) ? W[(size_t)k * D_IN_PROJ + col] : 0.f;
  }
  __syncthreads();
  int tx = tid % 16, ty = tid / 16;
  float acc[4][4] = {};
#pragma unroll 4
  for (int k = 0; k < 96; k++) {
    float a0 = As[ty * 4 + 0][k];
    float a1 = As[ty * 4 + 1][k];
    float a2 = As[ty * 4 + 2][k];
    float a3 = As[ty * 4 + 3][k];
    float4 bv = *(const float4*)&Bs[k][tx * 4];
    acc[0][0] += a0 * bv.x; acc[0][1] += a0 * bv.y; acc[0][2] += a0 * bv.z; acc[0][3] += a0 * bv.w;
    acc[1][0] += a1 * bv.x; acc[1][1] += a1 * bv.y; acc[1][2] += a1 * bv.z; acc[1][3] += a1 * bv.w;
    acc[2][0] += a2 * bv.x; acc[2][1] += a2 * bv.y; acc[2][2] += a2 * bv.z; acc[2][3] += a2 * bv.w;
    acc[3][0] += a3 * bv.x; acc[3][1] += a3 * bv.y; acc[3][2] += a3 * bv.z; acc[3][3] += a3 * bv.w;
  }
#pragma unroll
  for (int i = 0; i < 4; i++) {
#pragma unroll
    for (int j = 0; j < 4; j++) {
      int col = n0 + tx * 4 + j;
      if (col < D_IN_PROJ)
        C[(size_t)(m0 + ty * 4 + i) * D_IN_PROJ + col] = acc[i][j];
    }
  }
}

// ---------------------------------------------------------------------------
// K5: fused causal-conv + silu + softplus(dt) + SSM scan. Block per (b,h).
// ---------------------------------------------------------------------------
__global__ __launch_bounds__(256) void k5_scan(
    const float* __restrict__ zx, const float* __restrict__ conv_w,
    const float* __restrict__ conv_b, const float* __restrict__ dt_bias,
    const float* __restrict__ A_log, const float* __restrict__ Dparam,
    float* __restrict__ y) {
  int b = blockIdx.x;  // 96
  int h = blockIdx.y;  // 6
  int tid = threadIdx.x;

  __shared__ float ring[4][160];   // raw xBC window for conv
  __shared__ float cur[160];       // post-conv+silu: x[0:32] B[32:96] C[96:160]
  __shared__ float dt_s[2], dA_s[2];

  float cw0 = 0, cw1 = 0, cw2 = 0, cw3 = 0, cb = 0;
  int col = 0;
  if (tid < 160) {
    int c;
    if (tid < 32)       c = h * 32 + tid;
    else if (tid < 96)  c = 192 + h * 64 + (tid - 32);
    else                c = 576 + h * 64 + (tid - 96);
    col = 192 + c;  // column in zxbcdt
    cw0 = conv_w[c * 4 + 0];
    cw1 = conv_w[c * 4 + 1];
    cw2 = conv_w[c * 4 + 2];
    cw3 = conv_w[c * 4 + 3];
    cb = conv_b[c];
  }
  float Ah = -expf(A_log[h]);
  float Dh = Dparam[h];
  float dtb = dt_bias[h];

  float s[8];
#pragma unroll
  for (int i = 0; i < 8; i++) s[i] = 0.f;
  int p = tid >> 3, ng = tid & 7;

  const float* zrow = zx + (size_t)b * 160 * D_IN_PROJ;

  for (int t = 0; t < 160; t++) {
    if (tid < 160) ring[t & 3][tid] = zrow[(size_t)t * D_IN_PROJ + col];
    if (tid == 160) {
      float raw = zrow[(size_t)t * D_IN_PROJ + 1152 + h] + dtb;
      float dtv = softplusf(raw);
      dt_s[t & 1] = dtv;
      dA_s[t & 1] = expf(dtv * Ah);
    }
    __syncthreads();
    if (tid < 160) {
      float acc = cb + ring[t & 3][tid] * cw3;
      if (t >= 1) acc += ring[(t - 1) & 3][tid] * cw2;
      if (t >= 2) acc += ring[(t - 2) & 3][tid] * cw1;
      if (t >= 3) acc += ring[(t - 3) & 3][tid] * cw0;
      cur[tid] = siluf(acc);
    }
    __syncthreads();
    float dtv = dt_s[t & 1], dAv = dA_s[t & 1];
    float xv = cur[p];
    float dtx = dtv * xv;
    float part = 0.f;
#pragma unroll
    for (int i = 0; i < 8; i++) {
      int n = ng * 8 + i;
      s[i] = s[i] * dAv + dtx * cur[32 + n];
      part += s[i] * cur[96 + n];
    }
    part += __shfl_xor(part, 1);
    part += __shfl_xor(part, 2);
    part += __shfl_xor(part, 4);
    if (ng == 0)
      y[((size_t)(b * 160 + t)) * D_INNER + h * 32 + p] = part + Dh * xv;
    // no barrier needed here: next iteration's ring/dt writes target slots
    // not read after the second barrier (parity/ring-depth separation)
  }
}

// ---------------------------------------------------------------------------
// K6: gated RMSNorm + out_proj + partial time-mean. Block per (b, chunk of 20 t).
// ---------------------------------------------------------------------------
__global__ __launch_bounds__(256) void k6_head(
    const float* __restrict__ y, const float* __restrict__ zx,
    const float* __restrict__ norm_w, const float* __restrict__ out_proj,
    float* __restrict__ e_part) {
  int b = blockIdx.x;
  int ch = blockIdx.y;  // 8 chunks x 20 timesteps
  int tid = threadIdx.x;
  __shared__ float yn[192];
  __shared__ float eacc[2][96];
  __shared__ float rfac;
  float ereg = 0.f;

  for (int tt = 0; tt < 20; tt++) {
    int t = ch * 20 + tt;
    size_t row = (size_t)(b * 160 + t);
    if (tid < 192) {
      float yv = y[row * D_INNER + tid];
      float zg = zx[row * D_IN_PROJ + tid];
      yn[tid] = yv * siluf(zg);
    }
    __syncthreads();
    if (tid < 64) {
      float v0 = yn[tid], v1 = yn[tid + 64], v2 = yn[tid + 128];
      float ss = v0 * v0 + v1 * v1 + v2 * v2;
      ss += __shfl_xor(ss, 1);
      ss += __shfl_xor(ss, 2);
      ss += __shfl_xor(ss, 4);
      ss += __shfl_xor(ss, 8);
      ss += __shfl_xor(ss, 16);
      ss += __shfl_xor(ss, 32);
      if (tid == 0) rfac = rsqrtf(ss * (1.f / 192.f) + RMS_EPS);
    }
    __syncthreads();
    if (tid < 192) yn[tid] = yn[tid] * rfac * norm_w[tid];
    __syncthreads();
    if (tid < 192) {
      int d = tid % 96, half = tid / 96;
      float acc = 0.f;
      int k0 = half * 96;
      for (int k = k0; k < k0 + 96; k++) acc += yn[k] * out_proj[(size_t)k * 96 + d];
      eacc[half][d] = acc;
    }
    __syncthreads();
    if (tid < 96) ereg += eacc[0][tid] + eacc[1][tid];
    __syncthreads();
  }
  if (tid < 96) e_part[(size_t)ch * 9216 + b * 96 + tid] = ereg;
}

// ---------------------------------------------------------------------------
// K7: reduce chunks, final heads: x1, mu, sigma
// ---------------------------------------------------------------------------
__global__ __launch_bounds__(128) void k7_out(
    const float* __restrict__ e_part, const float* __restrict__ fcw,
    const float* __restrict__ fcb, const float* __restrict__ mu_w,
    const float* __restrict__ mu_b, const float* __restrict__ sg_w,
    const float* __restrict__ sg_b, float* __restrict__ out) {
  int b = blockIdx.x;
  int tid = threadIdx.x;
  __shared__ float em[96];
  __shared__ float x1[96];
  if (tid < 96) {
    float s = 0.f;
    for (int c = 0; c < 8; c++) s += e_part[(size_t)c * 9216 + b * 96 + tid];
    em[tid] = s * (1.f / 160.f);
  }
  __syncthreads();
  if (tid < 96) {
    float acc = fcb[tid];
    for (int k = 0; k < 96; k++) acc += em[k] * fcw[k * 96 + tid];
    float tv = tanhf(acc);
    float ev = (tv > 0.f) ? tv : expm1f(tv);
    x1[tid] = ev;
    out[b * 96 + tid] = ev;
  }
  __syncthreads();
  int j = tid & 63, which = tid >> 6;
  if (which == 0) {
    float acc = mu_b[j];
    for (int k = 0; k < 96; k++) acc += x1[k] * mu_w[k * 64 + j];
    out[9216 + b * 64 + j] = acc;
  } else {
    float acc = sg_b[j];
    for (int k = 0; k < 96; k++) acc += x1[k] * sg_w[k * 64 + j];
    float ev = (acc > 0.f) ? acc : expm1f(acc);
    out[9216 + 6144 + b * 64 + j] = ev + 1.f + 1e-14f;
  }
}

// ---------------------------------------------------------------------------
extern "C" void kernel_launch(void* const* d_in, const int* in_sizes, int n_in,
                              void* d_out, int out_size, void* d_ws,
                              size_t ws_size, hipStream_t stream) {
  const float* input      = (const float*)d_in[0];
  const int*   hem        = (const int*)d_in[1];
  const int*   subnet     = (const int*)d_in[2];
  const float* gine_w1    = (const float*)d_in[3];
  const float* gine_b1    = (const float*)d_in[4];
  const float* gine_w2    = (const float*)d_in[5];
  const float* gine_b2    = (const float*)d_in[6];
  const float* bn_w       = (const float*)d_in[7];
  const float* bn_b       = (const float*)d_in[8];
  const float* hem_emb    = (const float*)d_in[9];
  const float* subnet_emb = (const float*)d_in[10];
  const float* in_proj    = (const float*)d_in[11];
  const float* conv_w     = (const float*)d_in[12];
  const float* conv_b     = (const float*)d_in[13];
  const float* dt_bias    = (const float*)d_in[14];
  const float* A_log      = (const float*)d_in[15];
  const float* Dparam     = (const float*)d_in[16];
  const float* norm_w     = (const float*)d_in[17];
  const float* out_proj   = (const float*)d_in[18];
  const float* out_fc_w   = (const float*)d_in[19];
  const float* out_fc_b   = (const float*)d_in[20];
  const float* mu_w       = (const float*)d_in[21];
  const float* mu_b       = (const float*)d_in[22];
  const float* sigma_w    = (const float*)d_in[23];
  const float* sigma_b    = (const float*)d_in[24];

  float* ws = (float*)d_ws;
  float* gin    = ws;                  // 1,474,560
  float* z      = gin + 1474560;       // 1,474,560
  float* zx     = z + 1474560;         // 17,786,880
  float* y      = zx + 17786880;       // 2,949,120
  float* e_part = y + 2949120;         // 73,728
  float* outp = (float*)d_out;

  k1_agg<<<160, 256, 0, stream>>>(input, hem, subnet, hem_emb, subnet_emb, gin);
  k2_gine<<<160, 256, 0, stream>>>(gin, input, gine_w1, gine_b1, gine_w2,
                                   gine_b2, bn_w, bn_b, z);
  k3_gemm<<<dim3(240, 19), 256, 0, stream>>>(z, in_proj, zx);
  k5_scan<<<dim3(96, 6), 256, 0, stream>>>(zx, conv_w, conv_b, dt_bias, A_log,
                                           Dparam, y);
  k6_head<<<dim3(96, 8), 256, 0, stream>>>(y, zx, norm_w, out_proj, e_part);
  k7_out<<<96, 128, 0, stream>>>(e_part, out_fc_w, out_fc_b, mu_w, mu_b,
                                 sigma_w, sigma_b, outp);
}

// Round 2
// 398.401 us; speedup vs baseline: 1.2889x; 1.2889x over previous
//
#include <hip/hip_runtime.h>
#include <hip/hip_bf16.h>
#include <math.h>

// Problem constants
#define NB 96        // batch / nodes
#define TT 160       // sequence length
#define DD 96        // feature dim
#define D_STATE 64
#define D_CONV 4
#define HEADDIM 32
#define NGROUPS 6
#define D_INNER 192
#define NHEADS 6
#define EMB 24
#define DOUT 64
#define D_IN_PROJ 1158
#define CONV_DIM 960
#define TN 15360     // TT*DD = input row stride per node, also rows of z
#define BN_EPS 1e-5f
#define RMS_EPS 1e-5f

__device__ __forceinline__ float siluf(float x) { return x / (1.f + expf(-x)); }
__device__ __forceinline__ float softplusf(float x) {
    return fmaxf(x, 0.f) + log1pf(expf(-fabsf(x)));
}

// ---------------------------------------------------------------------------
// K1: per-t aggregation: a-embeddings, s1, s2, gin = xs + agg
// ---------------------------------------------------------------------------
__global__ __launch_bounds__(256) void k1_agg(
    const float* __restrict__ input, const int* __restrict__ hem,
    const int* __restrict__ subnet, const float* __restrict__ hem_emb,
    const float* __restrict__ subnet_emb, float* __restrict__ gin) {
  int t = blockIdx.x;
  __shared__ float xs[96 * 96];
  __shared__ float al[96 * 48];
  __shared__ float s1[48];
  __shared__ float s2[96 * 48];
  int tid = threadIdx.x;

  for (int o = tid; o < 96 * 96; o += 256) {
    int i = o / 96, d = o % 96;
    xs[o] = input[i * TN + t * 96 + d];
  }
  for (int o = tid; o < 96 * 48; o += 256) {
    int i = o / 48, c = o % 48;
    al[o] = (c < 24) ? hem_emb[hem[i] * 24 + c]
                     : subnet_emb[subnet[i] * 24 + (c - 24)];
  }
  __syncthreads();
  if (tid < 48) {
    float s = 0.f;
    for (int i = 0; i < 96; i++) s += fmaxf(xs[i * 96 + tid] + al[i * 48 + tid], 0.f);
    s1[tid] = s;
  }
  for (int o = tid; o < 96 * 48; o += 256) {
    int j = o / 48, c = o % 48;
    float av = al[j * 48 + c];
    float s = 0.f;
    for (int i = 0; i < 96; i++) s += fmaxf(xs[i * 96 + 48 + c] + av, 0.f);
    s2[o] = s;
  }
  __syncthreads();
  for (int o = tid; o < 96 * 96; o += 256) {
    int j = o / 96, d = o % 96;
    float aggv = (d < 48) ? s1[d] : s2[j * 48 + (d - 48)];
    gin[t * 9216 + o] = xs[o] + aggv;
  }
}

// ---------------------------------------------------------------------------
// K2: per-t GINE MLP + residual + node-batchnorm -> z (b-major layout)
// ---------------------------------------------------------------------------
__global__ __launch_bounds__(256) void k2_gine(
    const float* __restrict__ gin, const float* __restrict__ input,
    const float* __restrict__ W1, const float* __restrict__ b1,
    const float* __restrict__ W2, const float* __restrict__ b2,
    const float* __restrict__ bn_w, const float* __restrict__ bn_b,
    float* __restrict__ z) {
  int t = blockIdx.x;
  __shared__ float A[96 * 96];   // gin, later h
  __shared__ float Hd[96 * 96];  // hidden
  __shared__ float Wl[96 * 96];  // weights
  __shared__ float mu[96], rs[96];
  int tid = threadIdx.x;

  for (int o = tid; o < 9216; o += 256) A[o] = gin[t * 9216 + o];
  for (int o = tid; o < 9216; o += 256) Wl[o] = W1[o];
  __syncthreads();
  for (int o = tid; o < 9216; o += 256) {
    int j = o / 96, d = o % 96;
    float acc = b1[d];
    for (int k = 0; k < 96; k++) acc += A[j * 96 + k] * Wl[k * 96 + d];
    Hd[o] = fmaxf(acc, 0.f);
  }
  __syncthreads();
  for (int o = tid; o < 9216; o += 256) Wl[o] = W2[o];
  __syncthreads();
  for (int o = tid; o < 9216; o += 256) {
    int j = o / 96, d = o % 96;
    float acc = b2[d];
    for (int k = 0; k < 96; k++) acc += Hd[j * 96 + k] * Wl[k * 96 + d];
    acc += input[j * TN + t * 96 + d];  // + xs residual
    A[o] = acc;
  }
  __syncthreads();
  if (tid < 96) {
    float m = 0.f;
    for (int j = 0; j < 96; j++) m += A[j * 96 + tid];
    m *= (1.f / 96.f);
    float v = 0.f;
    for (int j = 0; j < 96; j++) { float dd = A[j * 96 + tid] - m; v += dd * dd; }
    v *= (1.f / 96.f);
    mu[tid] = m;
    rs[tid] = rsqrtf(v + BN_EPS);
  }
  __syncthreads();
  for (int o = tid; o < 9216; o += 256) {
    int j = o / 96, d = o % 96;
    float val = (A[o] - mu[d]) * rs[d] * bn_w[d] + bn_b[d];
    z[j * TN + t * 96 + d] = val;  // z[b][l][d]
  }
}

// ---------------------------------------------------------------------------
// K3: in_proj GEMM: (15360 x 96) @ (96 x 1158) -> zxbcdt
// ---------------------------------------------------------------------------
__global__ __launch_bounds__(256) void k3_gemm(
    const float* __restrict__ Z, const float* __restrict__ W,
    float* __restrict__ C) {
  int m0 = blockIdx.x * 64;
  int n0 = blockIdx.y * 64;
  __shared__ float As[64][97];
  __shared__ float Bs[96][64];
  int tid = threadIdx.x;

  for (int o = tid; o < 64 * 96; o += 256) {
    int r = o / 96, k = o % 96;
    As[r][k] = Z[(size_t)(m0 + r) * 96 + k];
  }
  for (int o = tid; o < 96 * 64; o += 256) {
    int k = o / 64, c = o % 64;
    int col = n0 + c;
    Bs[k][c] = (col < D_IN_PROJ) ? W[(size_t)k * D_IN_PROJ + col] : 0.f;
  }
  __syncthreads();
  int tx = tid % 16, ty = tid / 16;
  float acc[4][4] = {};
#pragma unroll 4
  for (int k = 0; k < 96; k++) {
    float a0 = As[ty * 4 + 0][k];
    float a1 = As[ty * 4 + 1][k];
    float a2 = As[ty * 4 + 2][k];
    float a3 = As[ty * 4 + 3][k];
    float4 bv = *(const float4*)&Bs[k][tx * 4];
    acc[0][0] += a0 * bv.x; acc[0][1] += a0 * bv.y; acc[0][2] += a0 * bv.z; acc[0][3] += a0 * bv.w;
    acc[1][0] += a1 * bv.x; acc[1][1] += a1 * bv.y; acc[1][2] += a1 * bv.z; acc[1][3] += a1 * bv.w;
    acc[2][0] += a2 * bv.x; acc[2][1] += a2 * bv.y; acc[2][2] += a2 * bv.z; acc[2][3] += a2 * bv.w;
    acc[3][0] += a3 * bv.x; acc[3][1] += a3 * bv.y; acc[3][2] += a3 * bv.z; acc[3][3] += a3 * bv.w;
  }
#pragma unroll
  for (int i = 0; i < 4; i++) {
#pragma unroll
    for (int j = 0; j < 4; j++) {
      int col = n0 + tx * 4 + j;
      if (col < D_IN_PROJ)
        C[(size_t)(m0 + ty * 4 + i) * D_IN_PROJ + col] = acc[i][j];
    }
  }
}

// ---------------------------------------------------------------------------
// K5: fused causal-conv + silu + softplus(dt) + SSM scan. Block per (b,h).
// Chunked pipeline: bulk-load CHUNK timesteps -> LDS, conv in parallel,
// then CHUNK serial scan steps from LDS with no barriers inside the chunk.
// ---------------------------------------------------------------------------
#define CHUNK 16

__global__ __launch_bounds__(256) void k5_scan(
    const float* __restrict__ zx, const float* __restrict__ conv_w,
    const float* __restrict__ conv_b, const float* __restrict__ dt_bias,
    const float* __restrict__ A_log, const float* __restrict__ Dparam,
    float* __restrict__ y) {
  int b = blockIdx.x;  // 96
  int h = blockIdx.y;  // 6
  int tid = threadIdx.x;

  // raw[slot][c]: slot i holds timestep t0-3+i (slots 0..2 = history/pad)
  __shared__ float raw[CHUNK + 3][160];
  __shared__ float cur[CHUNK][160];  // x[0:32] B[32:96] C[96:160]
  __shared__ float rawdt[CHUNK];
  __shared__ float dt_s[CHUNK], dA_s[CHUNK];

  // per-channel conv weights for the conv threads (tid < 160, fixed channel)
  float cw0 = 0, cw1 = 0, cw2 = 0, cw3 = 0, cb = 0;
  if (tid < 160) {
    int c;
    if (tid < 32)       c = h * 32 + tid;
    else if (tid < 96)  c = 192 + h * 64 + (tid - 32);
    else                c = 576 + h * 64 + (tid - 96);
    cw0 = conv_w[c * 4 + 0];
    cw1 = conv_w[c * 4 + 1];
    cw2 = conv_w[c * 4 + 2];
    cw3 = conv_w[c * 4 + 3];
    cb = conv_b[c];
  }
  float Ah = -expf(A_log[h]);
  float Dh = Dparam[h];
  float dtb = dt_bias[h];

  // column bases in zxbcdt for the three segments (x, B, C), minus local c ofs
  int baseA = 192 + h * 32;        // + c        (c in [0,32))
  int baseB = 352 + h * 64;        // + c        (c in [32,96))
  int baseC = 672 + h * 64;        // + c        (c in [96,160))

  const float* zrow = zx + (size_t)b * 160 * D_IN_PROJ;

  // zero the 3 history slots
  for (int o = tid; o < 3 * 160; o += 256) raw[o / 160][o % 160] = 0.f;

  float s[8];
#pragma unroll
  for (int i = 0; i < 8; i++) s[i] = 0.f;
  int p = tid >> 3, ng = tid & 7;

  for (int ch = 0; ch < 10; ch++) {
    int t0 = ch * CHUNK;
    // ---- load phase: CHUNK rows x 160 cols as float4 (640 vectors) ----
    for (int v = tid; v < (CHUNK * 160) / 4; v += 256) {
      int tt = v / 40;
      int c = (v % 40) * 4;  // segment boundaries at 32/96 are 4-aligned
      int col = c + ((c < 32) ? baseA : (c < 96) ? baseB : baseC);
      float4 val = *(const float4*)&zrow[(size_t)(t0 + tt) * D_IN_PROJ + col];
      *(float4*)&raw[3 + tt][c] = val;
    }
    if (tid < CHUNK)
      rawdt[tid] = zrow[(size_t)(t0 + tid) * D_IN_PROJ + 1152 + h];
    __syncthreads();

    // ---- conv + silu (waves 0-2) ; dt/dA (wave 3) ----
    if (tid < 160) {
#pragma unroll
      for (int tt = 0; tt < CHUNK; tt++) {
        float acc = cb + raw[tt + 0][tid] * cw0 + raw[tt + 1][tid] * cw1 +
                    raw[tt + 2][tid] * cw2 + raw[tt + 3][tid] * cw3;
        cur[tt][tid] = siluf(acc);
      }
    } else if (tid >= 192 && tid < 192 + CHUNK) {
      int tt = tid - 192;
      float dtv = softplusf(rawdt[tt] + dtb);
      dt_s[tt] = dtv;
      dA_s[tt] = expf(dtv * Ah);
    }
    __syncthreads();

    // ---- shift history: raw[16..18] -> raw[0..2] (conv reads are done) ----
    for (int v = tid; v < (3 * 160) / 4; v += 256) {
      int sl = v / 40;
      int c = (v % 40) * 4;
      *(float4*)&raw[sl][c] = *(const float4*)&raw[CHUNK + sl][c];
    }

    // ---- scan: CHUNK serial steps, LDS reads only, no barriers ----
    for (int tt = 0; tt < CHUNK; tt++) {
      float dtv = dt_s[tt], dAv = dA_s[tt];
      float xv = cur[tt][p];
      float dtx = dtv * xv;
      const float4* Bp = (const float4*)&cur[tt][32 + ng * 8];
      const float4* Cp = (const float4*)&cur[tt][96 + ng * 8];
      float4 b0 = Bp[0], b1 = Bp[1];
      float4 c0 = Cp[0], c1 = Cp[1];
      float part;
      s[0] = s[0] * dAv + dtx * b0.x;
      s[1] = s[1] * dAv + dtx * b0.y;
      s[2] = s[2] * dAv + dtx * b0.z;
      s[3] = s[3] * dAv + dtx * b0.w;
      s[4] = s[4] * dAv + dtx * b1.x;
      s[5] = s[5] * dAv + dtx * b1.y;
      s[6] = s[6] * dAv + dtx * b1.z;
      s[7] = s[7] * dAv + dtx * b1.w;
      part = s[0] * c0.x + s[1] * c0.y + s[2] * c0.z + s[3] * c0.w +
             s[4] * c1.x + s[5] * c1.y + s[6] * c1.z + s[7] * c1.w;
      part += __shfl_xor(part, 1);
      part += __shfl_xor(part, 2);
      part += __shfl_xor(part, 4);
      if (ng == 0)
        y[((size_t)(b * 160 + t0 + tt)) * D_INNER + h * 32 + p] = part + Dh * xv;
    }
    __syncthreads();  // protect raw/cur before next chunk's load/conv
  }
}

// ---------------------------------------------------------------------------
// K6: gated RMSNorm + out_proj + partial time-mean. Block per (b, chunk of 20 t).
// ---------------------------------------------------------------------------
__global__ __launch_bounds__(256) void k6_head(
    const float* __restrict__ y, const float* __restrict__ zx,
    const float* __restrict__ norm_w, const float* __restrict__ out_proj,
    float* __restrict__ e_part) {
  int b = blockIdx.x;
  int ch = blockIdx.y;  // 8 chunks x 20 timesteps
  int tid = threadIdx.x;
  __shared__ float yn[192];
  __shared__ float eacc[2][96];
  __shared__ float rfac;
  float ereg = 0.f;

  for (int tt = 0; tt < 20; tt++) {
    int t = ch * 20 + tt;
    size_t row = (size_t)(b * 160 + t);
    if (tid < 192) {
      float yv = y[row * D_INNER + tid];
      float zg = zx[row * D_IN_PROJ + tid];
      yn[tid] = yv * siluf(zg);
    }
    __syncthreads();
    if (tid < 64) {
      float v0 = yn[tid], v1 = yn[tid + 64], v2 = yn[tid + 128];
      float ss = v0 * v0 + v1 * v1 + v2 * v2;
      ss += __shfl_xor(ss, 1);
      ss += __shfl_xor(ss, 2);
      ss += __shfl_xor(ss, 4);
      ss += __shfl_xor(ss, 8);
      ss += __shfl_xor(ss, 16);
      ss += __shfl_xor(ss, 32);
      if (tid == 0) rfac = rsqrtf(ss * (1.f / 192.f) + RMS_EPS);
    }
    __syncthreads();
    if (tid < 192) yn[tid] = yn[tid] * rfac * norm_w[tid];
    __syncthreads();
    if (tid < 192) {
      int d = tid % 96, half = tid / 96;
      float acc = 0.f;
      int k0 = half * 96;
      for (int k = k0; k < k0 + 96; k++) acc += yn[k] * out_proj[(size_t)k * 96 + d];
      eacc[half][d] = acc;
    }
    __syncthreads();
    if (tid < 96) ereg += eacc[0][tid] + eacc[1][tid];
    __syncthreads();
  }
  if (tid < 96) e_part[(size_t)ch * 9216 + b * 96 + tid] = ereg;
}

// ---------------------------------------------------------------------------
// K7: reduce chunks, final heads: x1, mu, sigma
// ---------------------------------------------------------------------------
__global__ __launch_bounds__(128) void k7_out(
    const float* __restrict__ e_part, const float* __restrict__ fcw,
    const float* __restrict__ fcb, const float* __restrict__ mu_w,
    const float* __restrict__ mu_b, const float* __restrict__ sg_w,
    const float* __restrict__ sg_b, float* __restrict__ out) {
  int b = blockIdx.x;
  int tid = threadIdx.x;
  __shared__ float em[96];
  __shared__ float x1[96];
  if (tid < 96) {
    float s = 0.f;
    for (int c = 0; c < 8; c++) s += e_part[(size_t)c * 9216 + b * 96 + tid];
    em[tid] = s * (1.f / 160.f);
  }
  __syncthreads();
  if (tid < 96) {
    float acc = fcb[tid];
    for (int k = 0; k < 96; k++) acc += em[k] * fcw[k * 96 + tid];
    float tv = tanhf(acc);
    float ev = (tv > 0.f) ? tv : expm1f(tv);
    x1[tid] = ev;
    out[b * 96 + tid] = ev;
  }
  __syncthreads();
  int j = tid & 63, which = tid >> 6;
  if (which == 0) {
    float acc = mu_b[j];
    for (int k = 0; k < 96; k++) acc += x1[k] * mu_w[k * 64 + j];
    out[9216 + b * 64 + j] = acc;
  } else {
    float acc = sg_b[j];
    for (int k = 0; k < 96; k++) acc += x1[k] * sg_w[k * 64 + j];
    float ev = (acc > 0.f) ? acc : expm1f(acc);
    out[9216 + 6144 + b * 64 + j] = ev + 1.f + 1e-14f;
  }
}

// ---------------------------------------------------------------------------
extern "C" void kernel_launch(void* const* d_in, const int* in_sizes, int n_in,
                              void* d_out, int out_size, void* d_ws,
                              size_t ws_size, hipStream_t stream) {
  const float* input      = (const float*)d_in[0];
  const int*   hem        = (const int*)d_in[1];
  const int*   subnet     = (const int*)d_in[2];
  const float* gine_w1    = (const float*)d_in[3];
  const float* gine_b1    = (const float*)d_in[4];
  const float* gine_w2    = (const float*)d_in[5];
  const float* gine_b2    = (const float*)d_in[6];
  const float* bn_w       = (const float*)d_in[7];
  const float* bn_b       = (const float*)d_in[8];
  const float* hem_emb    = (const float*)d_in[9];
  const float* subnet_emb = (const float*)d_in[10];
  const float* in_proj    = (const float*)d_in[11];
  const float* conv_w     = (const float*)d_in[12];
  const float* conv_b     = (const float*)d_in[13];
  const float* dt_bias    = (const float*)d_in[14];
  const float* A_log      = (const float*)d_in[15];
  const float* Dparam     = (const float*)d_in[16];
  const float* norm_w     = (const float*)d_in[17];
  const float* out_proj   = (const float*)d_in[18];
  const float* out_fc_w   = (const float*)d_in[19];
  const float* out_fc_b   = (const float*)d_in[20];
  const float* mu_w       = (const float*)d_in[21];
  const float* mu_b       = (const float*)d_in[22];
  const float* sigma_w    = (const float*)d_in[23];
  const float* sigma_b    = (const float*)d_in[24];

  float* ws = (float*)d_ws;
  float* gin    = ws;                  // 1,474,560
  float* z      = gin + 1474560;       // 1,474,560
  float* zx     = z + 1474560;         // 17,786,880
  float* y      = zx + 17786880;       // 2,949,120
  float* e_part = y + 2949120;         // 73,728
  float* outp = (float*)d_out;

  k1_agg<<<160, 256, 0, stream>>>(input, hem, subnet, hem_emb, subnet_emb, gin);
  k2_gine<<<160, 256, 0, stream>>>(gin, input, gine_w1, gine_b1, gine_w2,
                                   gine_b2, bn_w, bn_b, z);
  k3_gemm<<<dim3(240, 19), 256, 0, stream>>>(z, in_proj, zx);
  k5_scan<<<dim3(96, 6), 256, 0, stream>>>(zx, conv_w, conv_b, dt_bias, A_log,
                                           Dparam, y);
  k6_head<<<dim3(96, 8), 256, 0, stream>>>(y, zx, norm_w, out_proj, e_part);
  k7_out<<<96, 128, 0, stream>>>(e_part, out_fc_w, out_fc_b, mu_w, mu_b,
                                 sigma_w, sigma_b, outp);
}

// Round 3
// 293.405 us; speedup vs baseline: 1.7502x; 1.3579x over previous
//
#include <hip/hip_runtime.h>
#include <hip/hip_bf16.h>
#include <math.h>

// Problem constants
#define NB 96        // batch / nodes
#define TT 160       // sequence length
#define DD 96        // feature dim
#define D_STATE 64
#define D_CONV 4
#define HEADDIM 32
#define NGROUPS 6
#define D_INNER 192
#define NHEADS 6
#define EMB 24
#define DOUT 64
#define D_IN_PROJ 1158
#define CONV_DIM 960
#define TN 15360     // TT*DD = input row stride per node, also rows of z
#define BN_EPS 1e-5f
#define RMS_EPS 1e-5f

__device__ __forceinline__ float siluf(float x) { return x / (1.f + expf(-x)); }
__device__ __forceinline__ float softplusf(float x) {
    return fmaxf(x, 0.f) + log1pf(expf(-fabsf(x)));
}

// ---------------------------------------------------------------------------
// K1: per-t aggregation: a-embeddings, s1, s2, gin = xs + agg
// ---------------------------------------------------------------------------
__global__ __launch_bounds__(256) void k1_agg(
    const float* __restrict__ input, const int* __restrict__ hem,
    const int* __restrict__ subnet, const float* __restrict__ hem_emb,
    const float* __restrict__ subnet_emb, float* __restrict__ gin) {
  int t = blockIdx.x;
  __shared__ float xs[96 * 96];
  __shared__ float al[96 * 48];
  __shared__ float s1[48];
  __shared__ float s2[96 * 48];
  int tid = threadIdx.x;

  for (int o = tid; o < 96 * 96; o += 256) {
    int i = o / 96, d = o % 96;
    xs[o] = input[i * TN + t * 96 + d];
  }
  for (int o = tid; o < 96 * 48; o += 256) {
    int i = o / 48, c = o % 48;
    al[o] = (c < 24) ? hem_emb[hem[i] * 24 + c]
                     : subnet_emb[subnet[i] * 24 + (c - 24)];
  }
  __syncthreads();
  if (tid < 48) {
    float s = 0.f;
    for (int i = 0; i < 96; i++) s += fmaxf(xs[i * 96 + tid] + al[i * 48 + tid], 0.f);
    s1[tid] = s;
  }
  for (int o = tid; o < 96 * 48; o += 256) {
    int j = o / 48, c = o % 48;
    float av = al[j * 48 + c];
    float s = 0.f;
    for (int i = 0; i < 96; i++) s += fmaxf(xs[i * 96 + 48 + c] + av, 0.f);
    s2[o] = s;
  }
  __syncthreads();
  for (int o = tid; o < 96 * 96; o += 256) {
    int j = o / 96, d = o % 96;
    float aggv = (d < 48) ? s1[d] : s2[j * 48 + (d - 48)];
    gin[t * 9216 + o] = xs[o] + aggv;
  }
}

// ---------------------------------------------------------------------------
// K2a: fused 2-layer GINE MLP + residual over 64-row tiles.
// H (output) may alias gin: each block reads only its own 64 rows (into LDS)
// before writing them, and no other block touches those rows.
// ---------------------------------------------------------------------------
__global__ __launch_bounds__(256) void k2_mlp(
    const float* __restrict__ gin, const float* __restrict__ input,
    const float* __restrict__ W1, const float* __restrict__ b1,
    const float* __restrict__ W2, const float* __restrict__ b2,
    float* __restrict__ H) {
  int r0 = blockIdx.x * 64;
  __shared__ float As[64][97];  // stride 97: avoid 4-way bank alias on ty-broadcast reads
  __shared__ float Bs[96][96];  // W1, then W2
  __shared__ float Hd[64][97];
  int tid = threadIdx.x;
  int tx = tid & 15, ty = tid >> 4;
  int c0 = tx * 6;
  int rb = ty * 4;

  for (int o = tid; o < 64 * 96; o += 256) As[o / 96][o % 96] = gin[(size_t)r0 * 96 + o];
  for (int o = tid; o < 96 * 96; o += 256) ((float*)Bs)[o] = W1[o];
  __syncthreads();

  float acc[4][6];
#pragma unroll
  for (int i = 0; i < 4; i++)
#pragma unroll
    for (int j = 0; j < 6; j++) acc[i][j] = b1[c0 + j];

#pragma unroll 4
  for (int k = 0; k < 96; k++) {
    float a0 = As[rb + 0][k], a1 = As[rb + 1][k], a2 = As[rb + 2][k], a3 = As[rb + 3][k];
    float b[6];
#pragma unroll
    for (int j = 0; j < 6; j++) b[j] = Bs[k][c0 + j];
#pragma unroll
    for (int j = 0; j < 6; j++) {
      acc[0][j] += a0 * b[j];
      acc[1][j] += a1 * b[j];
      acc[2][j] += a2 * b[j];
      acc[3][j] += a3 * b[j];
    }
  }
#pragma unroll
  for (int i = 0; i < 4; i++)
#pragma unroll
    for (int j = 0; j < 6; j++) Hd[rb + i][c0 + j] = fmaxf(acc[i][j], 0.f);
  __syncthreads();
  for (int o = tid; o < 96 * 96; o += 256) ((float*)Bs)[o] = W2[o];
#pragma unroll
  for (int i = 0; i < 4; i++)
#pragma unroll
    for (int j = 0; j < 6; j++) acc[i][j] = b2[c0 + j];
  __syncthreads();

#pragma unroll 4
  for (int k = 0; k < 96; k++) {
    float a0 = Hd[rb + 0][k], a1 = Hd[rb + 1][k], a2 = Hd[rb + 2][k], a3 = Hd[rb + 3][k];
    float b[6];
#pragma unroll
    for (int j = 0; j < 6; j++) b[j] = Bs[k][c0 + j];
#pragma unroll
    for (int j = 0; j < 6; j++) {
      acc[0][j] += a0 * b[j];
      acc[1][j] += a1 * b[j];
      acc[2][j] += a2 * b[j];
      acc[3][j] += a3 * b[j];
    }
  }
  // residual (+xs) and store
#pragma unroll
  for (int i = 0; i < 4; i++) {
    int r = r0 + rb + i;
    int t = r / 96, jn = r % 96;
    const float* resr = input + (size_t)jn * TN + t * 96 + c0;
#pragma unroll
    for (int j = 0; j < 6; j++)
      H[(size_t)r * 96 + c0 + j] = acc[i][j] + resr[j];
  }
}

// ---------------------------------------------------------------------------
// K2b: node-batchnorm per t (mean/var over 96 nodes per feature), write z
// in [b][l][d] layout.
// ---------------------------------------------------------------------------
__global__ __launch_bounds__(256) void k2_bn(
    const float* __restrict__ H, const float* __restrict__ bn_w,
    const float* __restrict__ bn_b, float* __restrict__ z) {
  int t = blockIdx.x;
  __shared__ float h[96 * 96];
  __shared__ float mu[96], rs[96];
  int tid = threadIdx.x;

  for (int o = tid; o < 9216; o += 256) h[o] = H[(size_t)t * 9216 + o];
  __syncthreads();
  if (tid < 96) {
    float m = 0.f;
    for (int j = 0; j < 96; j++) m += h[j * 96 + tid];
    m *= (1.f / 96.f);
    float v = 0.f;
    for (int j = 0; j < 96; j++) { float dd = h[j * 96 + tid] - m; v += dd * dd; }
    v *= (1.f / 96.f);
    mu[tid] = m;
    rs[tid] = rsqrtf(v + BN_EPS);
  }
  __syncthreads();
  for (int o = tid; o < 9216; o += 256) {
    int j = o / 96, d = o % 96;
    z[(size_t)j * TN + t * 96 + d] = (h[o] - mu[d]) * rs[d] * bn_w[d] + bn_b[d];
  }
}

// ---------------------------------------------------------------------------
// K3: in_proj GEMM: (15360 x 96) @ (96 x 1158) -> zxbcdt
// ---------------------------------------------------------------------------
__global__ __launch_bounds__(256) void k3_gemm(
    const float* __restrict__ Z, const float* __restrict__ W,
    float* __restrict__ C) {
  int m0 = blockIdx.x * 64;
  int n0 = blockIdx.y * 64;
  __shared__ float As[64][97];
  __shared__ float Bs[96][64];
  int tid = threadIdx.x;

  for (int o = tid; o < 64 * 96; o += 256) {
    int r = o / 96, k = o % 96;
    As[r][k] = Z[(size_t)(m0 + r) * 96 + k];
  }
  for (int o = tid; o < 96 * 64; o += 256) {
    int k = o / 64, c = o % 64;
    int col = n0 + c;
    Bs[k][c] = (col < D_IN_PROJ) ? W[(size_t)k * D_IN_PROJ + col] : 0.f;
  }
  __syncthreads();
  int tx = tid % 16, ty = tid / 16;
  float acc[4][4] = {};
#pragma unroll 4
  for (int k = 0; k < 96; k++) {
    float a0 = As[ty * 4 + 0][k];
    float a1 = As[ty * 4 + 1][k];
    float a2 = As[ty * 4 + 2][k];
    float a3 = As[ty * 4 + 3][k];
    float4 bv = *(const float4*)&Bs[k][tx * 4];
    acc[0][0] += a0 * bv.x; acc[0][1] += a0 * bv.y; acc[0][2] += a0 * bv.z; acc[0][3] += a0 * bv.w;
    acc[1][0] += a1 * bv.x; acc[1][1] += a1 * bv.y; acc[1][2] += a1 * bv.z; acc[1][3] += a1 * bv.w;
    acc[2][0] += a2 * bv.x; acc[2][1] += a2 * bv.y; acc[2][2] += a2 * bv.z; acc[2][3] += a2 * bv.w;
    acc[3][0] += a3 * bv.x; acc[3][1] += a3 * bv.y; acc[3][2] += a3 * bv.z; acc[3][3] += a3 * bv.w;
  }
#pragma unroll
  for (int i = 0; i < 4; i++) {
#pragma unroll
    for (int j = 0; j < 4; j++) {
      int col = n0 + tx * 4 + j;
      if (col < D_IN_PROJ)
        C[(size_t)(m0 + ty * 4 + i) * D_IN_PROJ + col] = acc[i][j];
    }
  }
}

// ---------------------------------------------------------------------------
// K5: fused causal-conv + silu + softplus(dt) + SSM scan. Block per (b,h).
// Chunked pipeline: bulk-load CHUNK timesteps -> LDS, conv in parallel,
// then CHUNK serial scan steps from LDS with no barriers inside the chunk.
// ---------------------------------------------------------------------------
#define CHUNK 16

__global__ __launch_bounds__(256) void k5_scan(
    const float* __restrict__ zx, const float* __restrict__ conv_w,
    const float* __restrict__ conv_b, const float* __restrict__ dt_bias,
    const float* __restrict__ A_log, const float* __restrict__ Dparam,
    float* __restrict__ y) {
  int b = blockIdx.x;  // 96
  int h = blockIdx.y;  // 6
  int tid = threadIdx.x;

  // raw[slot][c]: slot i holds timestep t0-3+i (slots 0..2 = history/pad)
  __shared__ float raw[CHUNK + 3][160];
  __shared__ float cur[CHUNK][160];  // x[0:32] B[32:96] C[96:160]
  __shared__ float rawdt[CHUNK];
  __shared__ float dt_s[CHUNK], dA_s[CHUNK];

  // per-channel conv weights for the conv threads (tid < 160, fixed channel)
  float cw0 = 0, cw1 = 0, cw2 = 0, cw3 = 0, cb = 0;
  if (tid < 160) {
    int c;
    if (tid < 32)       c = h * 32 + tid;
    else if (tid < 96)  c = 192 + h * 64 + (tid - 32);
    else                c = 576 + h * 64 + (tid - 96);
    cw0 = conv_w[c * 4 + 0];
    cw1 = conv_w[c * 4 + 1];
    cw2 = conv_w[c * 4 + 2];
    cw3 = conv_w[c * 4 + 3];
    cb = conv_b[c];
  }
  float Ah = -expf(A_log[h]);
  float Dh = Dparam[h];
  float dtb = dt_bias[h];

  // column bases in zxbcdt for the three segments (x, B, C), minus local c ofs
  int baseA = 192 + h * 32;        // + c        (c in [0,32))
  int baseB = 352 + h * 64;        // + c        (c in [32,96))
  int baseC = 672 + h * 64;        // + c        (c in [96,160))

  const float* zrow = zx + (size_t)b * 160 * D_IN_PROJ;

  // zero the 3 history slots
  for (int o = tid; o < 3 * 160; o += 256) raw[o / 160][o % 160] = 0.f;

  float s[8];
#pragma unroll
  for (int i = 0; i < 8; i++) s[i] = 0.f;
  int p = tid >> 3, ng = tid & 7;

  for (int ch = 0; ch < 10; ch++) {
    int t0 = ch * CHUNK;
    // ---- load phase: CHUNK rows x 160 cols as float4 (640 vectors) ----
    for (int v = tid; v < (CHUNK * 160) / 4; v += 256) {
      int tt = v / 40;
      int c = (v % 40) * 4;  // segment boundaries at 32/96 are 4-aligned
      int col = c + ((c < 32) ? baseA : (c < 96) ? baseB : baseC);
      float4 val = *(const float4*)&zrow[(size_t)(t0 + tt) * D_IN_PROJ + col];
      *(float4*)&raw[3 + tt][c] = val;
    }
    if (tid < CHUNK)
      rawdt[tid] = zrow[(size_t)(t0 + tid) * D_IN_PROJ + 1152 + h];
    __syncthreads();

    // ---- conv + silu (waves 0-2) ; dt/dA (wave 3) ----
    if (tid < 160) {
#pragma unroll
      for (int tt = 0; tt < CHUNK; tt++) {
        float acc = cb + raw[tt + 0][tid] * cw0 + raw[tt + 1][tid] * cw1 +
                    raw[tt + 2][tid] * cw2 + raw[tt + 3][tid] * cw3;
        cur[tt][tid] = siluf(acc);
      }
    } else if (tid >= 192 && tid < 192 + CHUNK) {
      int tt = tid - 192;
      float dtv = softplusf(rawdt[tt] + dtb);
      dt_s[tt] = dtv;
      dA_s[tt] = expf(dtv * Ah);
    }
    __syncthreads();

    // ---- shift history: raw[16..18] -> raw[0..2] (conv reads are done) ----
    for (int v = tid; v < (3 * 160) / 4; v += 256) {
      int sl = v / 40;
      int c = (v % 40) * 4;
      *(float4*)&raw[sl][c] = *(const float4*)&raw[CHUNK + sl][c];
    }

    // ---- scan: CHUNK serial steps, LDS reads only, no barriers ----
    for (int tt = 0; tt < CHUNK; tt++) {
      float dtv = dt_s[tt], dAv = dA_s[tt];
      float xv = cur[tt][p];
      float dtx = dtv * xv;
      const float4* Bp = (const float4*)&cur[tt][32 + ng * 8];
      const float4* Cp = (const float4*)&cur[tt][96 + ng * 8];
      float4 b0 = Bp[0], b1 = Bp[1];
      float4 c0 = Cp[0], c1 = Cp[1];
      float part;
      s[0] = s[0] * dAv + dtx * b0.x;
      s[1] = s[1] * dAv + dtx * b0.y;
      s[2] = s[2] * dAv + dtx * b0.z;
      s[3] = s[3] * dAv + dtx * b0.w;
      s[4] = s[4] * dAv + dtx * b1.x;
      s[5] = s[5] * dAv + dtx * b1.y;
      s[6] = s[6] * dAv + dtx * b1.z;
      s[7] = s[7] * dAv + dtx * b1.w;
      part = s[0] * c0.x + s[1] * c0.y + s[2] * c0.z + s[3] * c0.w +
             s[4] * c1.x + s[5] * c1.y + s[6] * c1.z + s[7] * c1.w;
      part += __shfl_xor(part, 1);
      part += __shfl_xor(part, 2);
      part += __shfl_xor(part, 4);
      if (ng == 0)
        y[((size_t)(b * 160 + t0 + tt)) * D_INNER + h * 32 + p] = part + Dh * xv;
    }
    __syncthreads();  // protect raw/cur before next chunk's load/conv
  }
}

// ---------------------------------------------------------------------------
// K6: gated RMSNorm + out_proj + partial time-mean. Block per (b, chunk of 20 t).
// ---------------------------------------------------------------------------
__global__ __launch_bounds__(256) void k6_head(
    const float* __restrict__ y, const float* __restrict__ zx,
    const float* __restrict__ norm_w, const float* __restrict__ out_proj,
    float* __restrict__ e_part) {
  int b = blockIdx.x;
  int ch = blockIdx.y;  // 8 chunks x 20 timesteps
  int tid = threadIdx.x;
  __shared__ float yn[192];
  __shared__ float eacc[2][96];
  __shared__ float rfac;
  float ereg = 0.f;

  for (int tt = 0; tt < 20; tt++) {
    int t = ch * 20 + tt;
    size_t row = (size_t)(b * 160 + t);
    if (tid < 192) {
      float yv = y[row * D_INNER + tid];
      float zg = zx[row * D_IN_PROJ + tid];
      yn[tid] = yv * siluf(zg);
    }
    __syncthreads();
    if (tid < 64) {
      float v0 = yn[tid], v1 = yn[tid + 64], v2 = yn[tid + 128];
      float ss = v0 * v0 + v1 * v1 + v2 * v2;
      ss += __shfl_xor(ss, 1);
      ss += __shfl_xor(ss, 2);
      ss += __shfl_xor(ss, 4);
      ss += __shfl_xor(ss, 8);
      ss += __shfl_xor(ss, 16);
      ss += __shfl_xor(ss, 32);
      if (tid == 0) rfac = rsqrtf(ss * (1.f / 192.f) + RMS_EPS);
    }
    __syncthreads();
    if (tid < 192) yn[tid] = yn[tid] * rfac * norm_w[tid];
    __syncthreads();
    if (tid < 192) {
      int d = tid % 96, half = tid / 96;
      float acc = 0.f;
      int k0 = half * 96;
      for (int k = k0; k < k0 + 96; k++) acc += yn[k] * out_proj[(size_t)k * 96 + d];
      eacc[half][d] = acc;
    }
    __syncthreads();
    if (tid < 96) ereg += eacc[0][tid] + eacc[1][tid];
    __syncthreads();
  }
  if (tid < 96) e_part[(size_t)ch * 9216 + b * 96 + tid] = ereg;
}

// ---------------------------------------------------------------------------
// K7: reduce chunks, final heads: x1, mu, sigma
// ---------------------------------------------------------------------------
__global__ __launch_bounds__(128) void k7_out(
    const float* __restrict__ e_part, const float* __restrict__ fcw,
    const float* __restrict__ fcb, const float* __restrict__ mu_w,
    const float* __restrict__ mu_b, const float* __restrict__ sg_w,
    const float* __restrict__ sg_b, float* __restrict__ out) {
  int b = blockIdx.x;
  int tid = threadIdx.x;
  __shared__ float em[96];
  __shared__ float x1[96];
  if (tid < 96) {
    float s = 0.f;
    for (int c = 0; c < 8; c++) s += e_part[(size_t)c * 9216 + b * 96 + tid];
    em[tid] = s * (1.f / 160.f);
  }
  __syncthreads();
  if (tid < 96) {
    float acc = fcb[tid];
    for (int k = 0; k < 96; k++) acc += em[k] * fcw[k * 96 + tid];
    float tv = tanhf(acc);
    float ev = (tv > 0.f) ? tv : expm1f(tv);
    x1[tid] = ev;
    out[b * 96 + tid] = ev;
  }
  __syncthreads();
  int j = tid & 63, which = tid >> 6;
  if (which == 0) {
    float acc = mu_b[j];
    for (int k = 0; k < 96; k++) acc += x1[k] * mu_w[k * 64 + j];
    out[9216 + b * 64 + j] = acc;
  } else {
    float acc = sg_b[j];
    for (int k = 0; k < 96; k++) acc += x1[k] * sg_w[k * 64 + j];
    float ev = (acc > 0.f) ? acc : expm1f(acc);
    out[9216 + 6144 + b * 64 + j] = ev + 1.f + 1e-14f;
  }
}

// ---------------------------------------------------------------------------
extern "C" void kernel_launch(void* const* d_in, const int* in_sizes, int n_in,
                              void* d_out, int out_size, void* d_ws,
                              size_t ws_size, hipStream_t stream) {
  const float* input      = (const float*)d_in[0];
  const int*   hem        = (const int*)d_in[1];
  const int*   subnet     = (const int*)d_in[2];
  const float* gine_w1    = (const float*)d_in[3];
  const float* gine_b1    = (const float*)d_in[4];
  const float* gine_w2    = (const float*)d_in[5];
  const float* gine_b2    = (const float*)d_in[6];
  const float* bn_w       = (const float*)d_in[7];
  const float* bn_b       = (const float*)d_in[8];
  const float* hem_emb    = (const float*)d_in[9];
  const float* subnet_emb = (const float*)d_in[10];
  const float* in_proj    = (const float*)d_in[11];
  const float* conv_w     = (const float*)d_in[12];
  const float* conv_b     = (const float*)d_in[13];
  const float* dt_bias    = (const float*)d_in[14];
  const float* A_log      = (const float*)d_in[15];
  const float* Dparam     = (const float*)d_in[16];
  const float* norm_w     = (const float*)d_in[17];
  const float* out_proj   = (const float*)d_in[18];
  const float* out_fc_w   = (const float*)d_in[19];
  const float* out_fc_b   = (const float*)d_in[20];
  const float* mu_w       = (const float*)d_in[21];
  const float* mu_b       = (const float*)d_in[22];
  const float* sigma_w    = (const float*)d_in[23];
  const float* sigma_b    = (const float*)d_in[24];

  float* ws = (float*)d_ws;
  float* gin    = ws;                  // 1,474,560  (k2_mlp output H aliases this)
  float* z      = gin + 1474560;       // 1,474,560
  float* zx     = z + 1474560;         // 17,786,880
  float* y      = zx + 17786880;       // 2,949,120
  float* e_part = y + 2949120;         // 73,728
  float* outp = (float*)d_out;

  k1_agg<<<160, 256, 0, stream>>>(input, hem, subnet, hem_emb, subnet_emb, gin);
  k2_mlp<<<240, 256, 0, stream>>>(gin, input, gine_w1, gine_b1, gine_w2,
                                  gine_b2, /*H=*/gin);
  k2_bn<<<160, 256, 0, stream>>>(gin, bn_w, bn_b, z);
  k3_gemm<<<dim3(240, 19), 256, 0, stream>>>(z, in_proj, zx);
  k5_scan<<<dim3(96, 6), 256, 0, stream>>>(zx, conv_w, conv_b, dt_bias, A_log,
                                           Dparam, y);
  k6_head<<<dim3(96, 8), 256, 0, stream>>>(y, zx, norm_w, out_proj, e_part);
  k7_out<<<96, 128, 0, stream>>>(e_part, out_fc_w, out_fc_b, mu_w, mu_b,
                                 sigma_w, sigma_b, outp);
}

// Round 4
// 237.088 us; speedup vs baseline: 2.1659x; 1.2375x over previous
//
#include <hip/hip_runtime.h>
#include <hip/hip_bf16.h>
#include <math.h>

// Problem constants
#define NB 96        // batch / nodes
#define TT 160       // sequence length
#define DD 96        // feature dim
#define D_STATE 64
#define D_CONV 4
#define HEADDIM 32
#define NGROUPS 6
#define D_INNER 192
#define NHEADS 6
#define EMB 24
#define DOUT 64
#define D_IN_PROJ 1158
#define CONV_DIM 960
#define TN 15360     // TT*DD = input row stride per node, also rows of z
#define BN_EPS 1e-5f
#define RMS_EPS 1e-5f

typedef __attribute__((ext_vector_type(8))) short short8;
typedef __attribute__((ext_vector_type(4))) float f32x4;

__device__ __forceinline__ float siluf(float x) { return x / (1.f + expf(-x)); }
__device__ __forceinline__ float softplusf(float x) {
    return fmaxf(x, 0.f) + log1pf(expf(-fabsf(x)));
}
__device__ __forceinline__ unsigned short bf16r(float x) {
  union { __hip_bfloat16 h; unsigned short u; } cv;
  cv.h = __float2bfloat16(x);
  return cv.u;
}
__device__ __forceinline__ unsigned int pack_bf2(float a, float b) {
  return (unsigned int)bf16r(a) | ((unsigned int)bf16r(b) << 16);
}

// ---------------------------------------------------------------------------
// K1: per-t aggregation: a-embeddings, s1, s2, gin = xs + agg
// ---------------------------------------------------------------------------
__global__ __launch_bounds__(256) void k1_agg(
    const float* __restrict__ input, const int* __restrict__ hem,
    const int* __restrict__ subnet, const float* __restrict__ hem_emb,
    const float* __restrict__ subnet_emb, float* __restrict__ gin) {
  int t = blockIdx.x;
  __shared__ float xs[96 * 96];
  __shared__ float al[96 * 48];
  __shared__ float s1[48];
  __shared__ float s2[96 * 48];
  int tid = threadIdx.x;

  for (int o = tid; o < 96 * 96; o += 256) {
    int i = o / 96, d = o % 96;
    xs[o] = input[i * TN + t * 96 + d];
  }
  for (int o = tid; o < 96 * 48; o += 256) {
    int i = o / 48, c = o % 48;
    al[o] = (c < 24) ? hem_emb[hem[i] * 24 + c]
                     : subnet_emb[subnet[i] * 24 + (c - 24)];
  }
  __syncthreads();
  if (tid < 48) {
    float s = 0.f;
    for (int i = 0; i < 96; i++) s += fmaxf(xs[i * 96 + tid] + al[i * 48 + tid], 0.f);
    s1[tid] = s;
  }
  for (int o = tid; o < 96 * 48; o += 256) {
    int j = o / 48, c = o % 48;
    float av = al[j * 48 + c];
    float s = 0.f;
    for (int i = 0; i < 96; i++) s += fmaxf(xs[i * 96 + 48 + c] + av, 0.f);
    s2[o] = s;
  }
  __syncthreads();
  for (int o = tid; o < 96 * 96; o += 256) {
    int j = o / 96, d = o % 96;
    float aggv = (d < 48) ? s1[d] : s2[j * 48 + (d - 48)];
    gin[t * 9216 + o] = xs[o] + aggv;
  }
}

// ---------------------------------------------------------------------------
// K2a: fused 2-layer GINE MLP + residual over 64-row tiles. H may alias gin.
// ---------------------------------------------------------------------------
__global__ __launch_bounds__(256) void k2_mlp(
    const float* __restrict__ gin, const float* __restrict__ input,
    const float* __restrict__ W1, const float* __restrict__ b1,
    const float* __restrict__ W2, const float* __restrict__ b2,
    float* __restrict__ H) {
  int r0 = blockIdx.x * 64;
  __shared__ float As[64][97];
  __shared__ float Bs[96][96];
  __shared__ float Hd[64][97];
  int tid = threadIdx.x;
  int tx = tid & 15, ty = tid >> 4;
  int c0 = tx * 6;
  int rb = ty * 4;

  for (int o = tid; o < 64 * 96; o += 256) As[o / 96][o % 96] = gin[(size_t)r0 * 96 + o];
  for (int o = tid; o < 96 * 96; o += 256) ((float*)Bs)[o] = W1[o];
  __syncthreads();

  float acc[4][6];
#pragma unroll
  for (int i = 0; i < 4; i++)
#pragma unroll
    for (int j = 0; j < 6; j++) acc[i][j] = b1[c0 + j];

#pragma unroll 4
  for (int k = 0; k < 96; k++) {
    float a0 = As[rb + 0][k], a1 = As[rb + 1][k], a2 = As[rb + 2][k], a3 = As[rb + 3][k];
    float b[6];
#pragma unroll
    for (int j = 0; j < 6; j++) b[j] = Bs[k][c0 + j];
#pragma unroll
    for (int j = 0; j < 6; j++) {
      acc[0][j] += a0 * b[j];
      acc[1][j] += a1 * b[j];
      acc[2][j] += a2 * b[j];
      acc[3][j] += a3 * b[j];
    }
  }
#pragma unroll
  for (int i = 0; i < 4; i++)
#pragma unroll
    for (int j = 0; j < 6; j++) Hd[rb + i][c0 + j] = fmaxf(acc[i][j], 0.f);
  __syncthreads();
  for (int o = tid; o < 96 * 96; o += 256) ((float*)Bs)[o] = W2[o];
#pragma unroll
  for (int i = 0; i < 4; i++)
#pragma unroll
    for (int j = 0; j < 6; j++) acc[i][j] = b2[c0 + j];
  __syncthreads();

#pragma unroll 4
  for (int k = 0; k < 96; k++) {
    float a0 = Hd[rb + 0][k], a1 = Hd[rb + 1][k], a2 = Hd[rb + 2][k], a3 = Hd[rb + 3][k];
    float b[6];
#pragma unroll
    for (int j = 0; j < 6; j++) b[j] = Bs[k][c0 + j];
#pragma unroll
    for (int j = 0; j < 6; j++) {
      acc[0][j] += a0 * b[j];
      acc[1][j] += a1 * b[j];
      acc[2][j] += a2 * b[j];
      acc[3][j] += a3 * b[j];
    }
  }
#pragma unroll
  for (int i = 0; i < 4; i++) {
    int r = r0 + rb + i;
    int t = r / 96, jn = r % 96;
    const float* resr = input + (size_t)jn * TN + t * 96 + c0;
#pragma unroll
    for (int j = 0; j < 6; j++)
      H[(size_t)r * 96 + c0 + j] = acc[i][j] + resr[j];
  }
}

// ---------------------------------------------------------------------------
// K2b: node-batchnorm per t, write z in [b][l][d] layout (fp32)
// ---------------------------------------------------------------------------
__global__ __launch_bounds__(256) void k2_bn(
    const float* __restrict__ H, const float* __restrict__ bn_w,
    const float* __restrict__ bn_b, float* __restrict__ z) {
  int t = blockIdx.x;
  __shared__ float h[96 * 96];
  __shared__ float mu[96], rs[96];
  int tid = threadIdx.x;

  for (int o = tid; o < 9216; o += 256) h[o] = H[(size_t)t * 9216 + o];
  __syncthreads();
  if (tid < 96) {
    float m = 0.f;
    for (int j = 0; j < 96; j++) m += h[j * 96 + tid];
    m *= (1.f / 96.f);
    float v = 0.f;
    for (int j = 0; j < 96; j++) { float dd = h[j * 96 + tid] - m; v += dd * dd; }
    v *= (1.f / 96.f);
    mu[tid] = m;
    rs[tid] = rsqrtf(v + BN_EPS);
  }
  __syncthreads();
  for (int o = tid; o < 9216; o += 256) {
    int j = o / 96, d = o % 96;
    z[(size_t)j * TN + t * 96 + d] = (h[o] - mu[d]) * rs[d] * bn_w[d] + bn_b[d];
  }
}

// ---------------------------------------------------------------------------
// K_convW: in_proj fp32 [96][1158] -> transposed bf16 WT [1158][96]
// ---------------------------------------------------------------------------
__global__ __launch_bounds__(256) void k_convW(
    const float* __restrict__ ip, unsigned short* __restrict__ WT) {
  int idx = blockIdx.x * 256 + threadIdx.x;
  if (idx < 96 * D_IN_PROJ) {
    int k = idx / D_IN_PROJ, n = idx - k * D_IN_PROJ;
    WT[(size_t)n * 96 + k] = bf16r(ip[idx]);
  }
}

// ---------------------------------------------------------------------------
// K3: in_proj GEMM via bf16 MFMA: (15360x96)@(96x1158) -> zxbcdt (fp32)
// Block tile 128x64, 4 waves x (2x4 frags of 16x16), single K=96 pass.
// Both A and B fragments use the same k-assignment g(q,j)=q*8+j, so the
// result is layout-wiring invariant (consistent bijection over k).
// ---------------------------------------------------------------------------
__global__ __launch_bounds__(256) void k3_mfma(
    const float* __restrict__ Z, const unsigned short* __restrict__ WT,
    float* __restrict__ C) {
  int m0 = blockIdx.x * 128;
  int n0 = blockIdx.y * 64;
  __shared__ unsigned short As[128][104];  // row-major [m][k], pad->104 (16B rows)
  __shared__ unsigned short Bs[64][104];   // [n][k]
  int tid = threadIdx.x;
  int lane = tid & 63, w = tid >> 6;

  // stage A: 128x96 fp32 -> bf16 (12 iters, float4 reads, 8B LDS writes)
  for (int o = tid; o < 128 * 24; o += 256) {
    int r = o / 24, c4 = (o % 24) * 4;
    float4 v = *(const float4*)&Z[(size_t)(m0 + r) * 96 + c4];
    unsigned int p0 = pack_bf2(v.x, v.y);
    unsigned int p1 = pack_bf2(v.z, v.w);
    *(uint2*)&As[r][c4] = make_uint2(p0, p1);
  }
  // stage B: 64 n-rows x 96 k, vector copy from WT (3 iters)
  for (int o = tid; o < 64 * 12; o += 256) {
    int nr = o / 12, seg = (o % 12) * 8;
    int n = n0 + nr;
    short8 v = {};
    if (n < D_IN_PROJ) v = *(const short8*)&WT[(size_t)n * 96 + seg];
    *(short8*)&Bs[nr][seg] = v;
  }
  __syncthreads();

  int q = lane >> 4, r16 = lane & 15;
  int wm = w * 32;
  f32x4 acc[2][4] = {};

#pragma unroll
  for (int ks = 0; ks < 3; ks++) {
    int k0 = ks * 32 + q * 8;
    short8 a0 = *(const short8*)&As[wm + r16][k0];
    short8 a1 = *(const short8*)&As[wm + 16 + r16][k0];
    short8 b0 = *(const short8*)&Bs[r16][k0];
    short8 b1 = *(const short8*)&Bs[16 + r16][k0];
    short8 b2 = *(const short8*)&Bs[32 + r16][k0];
    short8 b3 = *(const short8*)&Bs[48 + r16][k0];
    acc[0][0] = __builtin_amdgcn_mfma_f32_16x16x32_bf16(a0, b0, acc[0][0], 0, 0, 0);
    acc[0][1] = __builtin_amdgcn_mfma_f32_16x16x32_bf16(a0, b1, acc[0][1], 0, 0, 0);
    acc[0][2] = __builtin_amdgcn_mfma_f32_16x16x32_bf16(a0, b2, acc[0][2], 0, 0, 0);
    acc[0][3] = __builtin_amdgcn_mfma_f32_16x16x32_bf16(a0, b3, acc[0][3], 0, 0, 0);
    acc[1][0] = __builtin_amdgcn_mfma_f32_16x16x32_bf16(a1, b0, acc[1][0], 0, 0, 0);
    acc[1][1] = __builtin_amdgcn_mfma_f32_16x16x32_bf16(a1, b1, acc[1][1], 0, 0, 0);
    acc[1][2] = __builtin_amdgcn_mfma_f32_16x16x32_bf16(a1, b2, acc[1][2], 0, 0, 0);
    acc[1][3] = __builtin_amdgcn_mfma_f32_16x16x32_bf16(a1, b3, acc[1][3], 0, 0, 0);
  }

  // C/D layout (HW-verified): col = lane&15, row_in_frag = q*4 + reg
#pragma unroll
  for (int mf = 0; mf < 2; mf++) {
#pragma unroll
    for (int nf = 0; nf < 4; nf++) {
      int col = n0 + nf * 16 + r16;
      if (col < D_IN_PROJ) {
        int rowb = m0 + wm + mf * 16 + q * 4;
#pragma unroll
        for (int reg = 0; reg < 4; reg++)
          C[(size_t)(rowb + reg) * D_IN_PROJ + col] = acc[mf][nf][reg];
      }
    }
  }
}

// ---------------------------------------------------------------------------
// K5: fused causal-conv + silu + softplus(dt) + SSM scan. Block per (b,h).
// ---------------------------------------------------------------------------
#define CHUNK 16

__global__ __launch_bounds__(256) void k5_scan(
    const float* __restrict__ zx, const float* __restrict__ conv_w,
    const float* __restrict__ conv_b, const float* __restrict__ dt_bias,
    const float* __restrict__ A_log, const float* __restrict__ Dparam,
    float* __restrict__ y) {
  int b = blockIdx.x;  // 96
  int h = blockIdx.y;  // 6
  int tid = threadIdx.x;

  __shared__ float raw[CHUNK + 3][160];
  __shared__ float cur[CHUNK][160];  // x[0:32] B[32:96] C[96:160]
  __shared__ float rawdt[CHUNK];
  __shared__ float dt_s[CHUNK], dA_s[CHUNK];

  float cw0 = 0, cw1 = 0, cw2 = 0, cw3 = 0, cb = 0;
  if (tid < 160) {
    int c;
    if (tid < 32)       c = h * 32 + tid;
    else if (tid < 96)  c = 192 + h * 64 + (tid - 32);
    else                c = 576 + h * 64 + (tid - 96);
    cw0 = conv_w[c * 4 + 0];
    cw1 = conv_w[c * 4 + 1];
    cw2 = conv_w[c * 4 + 2];
    cw3 = conv_w[c * 4 + 3];
    cb = conv_b[c];
  }
  float Ah = -expf(A_log[h]);
  float Dh = Dparam[h];
  float dtb = dt_bias[h];

  int baseA = 192 + h * 32;
  int baseB = 352 + h * 64;
  int baseC = 672 + h * 64;

  const float* zrow = zx + (size_t)b * 160 * D_IN_PROJ;

  for (int o = tid; o < 3 * 160; o += 256) raw[o / 160][o % 160] = 0.f;

  float s[8];
#pragma unroll
  for (int i = 0; i < 8; i++) s[i] = 0.f;
  int p = tid >> 3, ng = tid & 7;

  for (int ch = 0; ch < 10; ch++) {
    int t0 = ch * CHUNK;
    for (int v = tid; v < (CHUNK * 160) / 4; v += 256) {
      int tt = v / 40;
      int c = (v % 40) * 4;
      int col = c + ((c < 32) ? baseA : (c < 96) ? baseB : baseC);
      float4 val = *(const float4*)&zrow[(size_t)(t0 + tt) * D_IN_PROJ + col];
      *(float4*)&raw[3 + tt][c] = val;
    }
    if (tid < CHUNK)
      rawdt[tid] = zrow[(size_t)(t0 + tid) * D_IN_PROJ + 1152 + h];
    __syncthreads();

    if (tid < 160) {
#pragma unroll
      for (int tt = 0; tt < CHUNK; tt++) {
        float acc = cb + raw[tt + 0][tid] * cw0 + raw[tt + 1][tid] * cw1 +
                    raw[tt + 2][tid] * cw2 + raw[tt + 3][tid] * cw3;
        cur[tt][tid] = siluf(acc);
      }
    } else if (tid >= 192 && tid < 192 + CHUNK) {
      int tt = tid - 192;
      float dtv = softplusf(rawdt[tt] + dtb);
      dt_s[tt] = dtv;
      dA_s[tt] = expf(dtv * Ah);
    }
    __syncthreads();

    for (int v = tid; v < (3 * 160) / 4; v += 256) {
      int sl = v / 40;
      int c = (v % 40) * 4;
      *(float4*)&raw[sl][c] = *(const float4*)&raw[CHUNK + sl][c];
    }

    for (int tt = 0; tt < CHUNK; tt++) {
      float dtv = dt_s[tt], dAv = dA_s[tt];
      float xv = cur[tt][p];
      float dtx = dtv * xv;
      const float4* Bp = (const float4*)&cur[tt][32 + ng * 8];
      const float4* Cp = (const float4*)&cur[tt][96 + ng * 8];
      float4 b0 = Bp[0], b1 = Bp[1];
      float4 c0 = Cp[0], c1 = Cp[1];
      float part;
      s[0] = s[0] * dAv + dtx * b0.x;
      s[1] = s[1] * dAv + dtx * b0.y;
      s[2] = s[2] * dAv + dtx * b0.z;
      s[3] = s[3] * dAv + dtx * b0.w;
      s[4] = s[4] * dAv + dtx * b1.x;
      s[5] = s[5] * dAv + dtx * b1.y;
      s[6] = s[6] * dAv + dtx * b1.z;
      s[7] = s[7] * dAv + dtx * b1.w;
      part = s[0] * c0.x + s[1] * c0.y + s[2] * c0.z + s[3] * c0.w +
             s[4] * c1.x + s[5] * c1.y + s[6] * c1.z + s[7] * c1.w;
      part += __shfl_xor(part, 1);
      part += __shfl_xor(part, 2);
      part += __shfl_xor(part, 4);
      if (ng == 0)
        y[((size_t)(b * 160 + t0 + tt)) * D_INNER + h * 32 + p] = part + Dh * xv;
    }
    __syncthreads();
  }
}

// ---------------------------------------------------------------------------
// K6: gated RMSNorm + out_proj + partial time-mean. Block per (b, chunk of 20 t).
// ---------------------------------------------------------------------------
__global__ __launch_bounds__(256) void k6_head(
    const float* __restrict__ y, const float* __restrict__ zx,
    const float* __restrict__ norm_w, const float* __restrict__ out_proj,
    float* __restrict__ e_part) {
  int b = blockIdx.x;
  int ch = blockIdx.y;
  int tid = threadIdx.x;
  __shared__ float yn[192];
  __shared__ float eacc[2][96];
  __shared__ float rfac;
  float ereg = 0.f;

  for (int tt = 0; tt < 20; tt++) {
    int t = ch * 20 + tt;
    size_t row = (size_t)(b * 160 + t);
    if (tid < 192) {
      float yv = y[row * D_INNER + tid];
      float zg = zx[row * D_IN_PROJ + tid];
      yn[tid] = yv * siluf(zg);
    }
    __syncthreads();
    if (tid < 64) {
      float v0 = yn[tid], v1 = yn[tid + 64], v2 = yn[tid + 128];
      float ss = v0 * v0 + v1 * v1 + v2 * v2;
      ss += __shfl_xor(ss, 1);
      ss += __shfl_xor(ss, 2);
      ss += __shfl_xor(ss, 4);
      ss += __shfl_xor(ss, 8);
      ss += __shfl_xor(ss, 16);
      ss += __shfl_xor(ss, 32);
      if (tid == 0) rfac = rsqrtf(ss * (1.f / 192.f) + RMS_EPS);
    }
    __syncthreads();
    if (tid < 192) yn[tid] = yn[tid] * rfac * norm_w[tid];
    __syncthreads();
    if (tid < 192) {
      int d = tid % 96, half = tid / 96;
      float acc = 0.f;
      int k0 = half * 96;
      for (int k = k0; k < k0 + 96; k++) acc += yn[k] * out_proj[(size_t)k * 96 + d];
      eacc[half][d] = acc;
    }
    __syncthreads();
    if (tid < 96) ereg += eacc[0][tid] + eacc[1][tid];
    __syncthreads();
  }
  if (tid < 96) e_part[(size_t)ch * 9216 + b * 96 + tid] = ereg;
}

// ---------------------------------------------------------------------------
// K7: reduce chunks, final heads: x1, mu, sigma
// ---------------------------------------------------------------------------
__global__ __launch_bounds__(128) void k7_out(
    const float* __restrict__ e_part, const float* __restrict__ fcw,
    const float* __restrict__ fcb, const float* __restrict__ mu_w,
    const float* __restrict__ mu_b, const float* __restrict__ sg_w,
    const float* __restrict__ sg_b, float* __restrict__ out) {
  int b = blockIdx.x;
  int tid = threadIdx.x;
  __shared__ float em[96];
  __shared__ float x1[96];
  if (tid < 96) {
    float s = 0.f;
    for (int c = 0; c < 8; c++) s += e_part[(size_t)c * 9216 + b * 96 + tid];
    em[tid] = s * (1.f / 160.f);
  }
  __syncthreads();
  if (tid < 96) {
    float acc = fcb[tid];
    for (int k = 0; k < 96; k++) acc += em[k] * fcw[k * 96 + tid];
    float tv = tanhf(acc);
    float ev = (tv > 0.f) ? tv : expm1f(tv);
    x1[tid] = ev;
    out[b * 96 + tid] = ev;
  }
  __syncthreads();
  int j = tid & 63, which = tid >> 6;
  if (which == 0) {
    float acc = mu_b[j];
    for (int k = 0; k < 96; k++) acc += x1[k] * mu_w[k * 64 + j];
    out[9216 + b * 64 + j] = acc;
  } else {
    float acc = sg_b[j];
    for (int k = 0; k < 96; k++) acc += x1[k] * sg_w[k * 64 + j];
    float ev = (acc > 0.f) ? acc : expm1f(acc);
    out[9216 + 6144 + b * 64 + j] = ev + 1.f + 1e-14f;
  }
}

// ---------------------------------------------------------------------------
extern "C" void kernel_launch(void* const* d_in, const int* in_sizes, int n_in,
                              void* d_out, int out_size, void* d_ws,
                              size_t ws_size, hipStream_t stream) {
  const float* input      = (const float*)d_in[0];
  const int*   hem        = (const int*)d_in[1];
  const int*   subnet     = (const int*)d_in[2];
  const float* gine_w1    = (const float*)d_in[3];
  const float* gine_b1    = (const float*)d_in[4];
  const float* gine_w2    = (const float*)d_in[5];
  const float* gine_b2    = (const float*)d_in[6];
  const float* bn_w       = (const float*)d_in[7];
  const float* bn_b       = (const float*)d_in[8];
  const float* hem_emb    = (const float*)d_in[9];
  const float* subnet_emb = (const float*)d_in[10];
  const float* in_proj    = (const float*)d_in[11];
  const float* conv_w     = (const float*)d_in[12];
  const float* conv_b     = (const float*)d_in[13];
  const float* dt_bias    = (const float*)d_in[14];
  const float* A_log      = (const float*)d_in[15];
  const float* Dparam     = (const float*)d_in[16];
  const float* norm_w     = (const float*)d_in[17];
  const float* out_proj   = (const float*)d_in[18];
  const float* out_fc_w   = (const float*)d_in[19];
  const float* out_fc_b   = (const float*)d_in[20];
  const float* mu_w       = (const float*)d_in[21];
  const float* mu_b       = (const float*)d_in[22];
  const float* sigma_w    = (const float*)d_in[23];
  const float* sigma_b    = (const float*)d_in[24];

  float* ws = (float*)d_ws;
  float* gin    = ws;                  // 1,474,560  (k2_mlp output H aliases this)
  float* z      = gin + 1474560;       // 1,474,560
  float* zx     = z + 1474560;         // 17,786,880
  float* y      = zx + 17786880;       // 2,949,120
  float* e_part = y + 2949120;         // 73,728
  // WT (bf16 in_proj^T, 1158x96 = 111168 shorts) aliases the TAIL of y:
  // stream order guarantees convW -> k3 (reads WT) -> k5 (overwrites y).
  unsigned short* WT = (unsigned short*)(y + 2893536);
  float* outp = (float*)d_out;

  k_convW<<<435, 256, 0, stream>>>(in_proj, WT);
  k1_agg<<<160, 256, 0, stream>>>(input, hem, subnet, hem_emb, subnet_emb, gin);
  k2_mlp<<<240, 256, 0, stream>>>(gin, input, gine_w1, gine_b1, gine_w2,
                                  gine_b2, /*H=*/gin);
  k2_bn<<<160, 256, 0, stream>>>(gin, bn_w, bn_b, z);
  k3_mfma<<<dim3(120, 19), 256, 0, stream>>>(z, WT, zx);
  k5_scan<<<dim3(96, 6), 256, 0, stream>>>(zx, conv_w, conv_b, dt_bias, A_log,
                                           Dparam, y);
  k6_head<<<dim3(96, 8), 256, 0, stream>>>(y, zx, norm_w, out_proj, e_part);
  k7_out<<<96, 128, 0, stream>>>(e_part, out_fc_w, out_fc_b, mu_w, mu_b,
                                 sigma_w, sigma_b, outp);
}

// Round 5
// 232.572 us; speedup vs baseline: 2.2080x; 1.0194x over previous
//
#include <hip/hip_runtime.h>
#include <hip/hip_bf16.h>
#include <math.h>

// Problem constants
#define NB 96        // batch / nodes
#define TT 160       // sequence length
#define DD 96        // feature dim
#define D_STATE 64
#define D_CONV 4
#define HEADDIM 32
#define NGROUPS 6
#define D_INNER 192
#define NHEADS 6
#define EMB 24
#define DOUT 64
#define D_IN_PROJ 1158
#define CONV_DIM 960
#define TN 15360     // TT*DD = input row stride per node, also rows of z
#define BN_EPS 1e-5f
#define RMS_EPS 1e-5f

typedef __attribute__((ext_vector_type(8))) short short8;
typedef __attribute__((ext_vector_type(4))) float f32x4;

__device__ __forceinline__ float siluf(float x) { return x / (1.f + expf(-x)); }
__device__ __forceinline__ float softplusf(float x) {
    return fmaxf(x, 0.f) + log1pf(expf(-fabsf(x)));
}
__device__ __forceinline__ unsigned short bf16r(float x) {
  union { __hip_bfloat16 h; unsigned short u; } cv;
  cv.h = __float2bfloat16(x);
  return cv.u;
}
__device__ __forceinline__ unsigned int pack_bf2(float a, float b) {
  return (unsigned int)bf16r(a) | ((unsigned int)bf16r(b) << 16);
}

// ---------------------------------------------------------------------------
// K1: per-t aggregation: a-embeddings, s1, s2, gin = xs + agg
// ---------------------------------------------------------------------------
__global__ __launch_bounds__(256) void k1_agg(
    const float* __restrict__ input, const int* __restrict__ hem,
    const int* __restrict__ subnet, const float* __restrict__ hem_emb,
    const float* __restrict__ subnet_emb, float* __restrict__ gin) {
  int t = blockIdx.x;
  __shared__ float xs[96 * 96];
  __shared__ float al[96 * 48];
  __shared__ float s1[48];
  __shared__ float s2[96 * 48];
  int tid = threadIdx.x;

  for (int o = tid; o < 96 * 96; o += 256) {
    int i = o / 96, d = o % 96;
    xs[o] = input[i * TN + t * 96 + d];
  }
  for (int o = tid; o < 96 * 48; o += 256) {
    int i = o / 48, c = o % 48;
    al[o] = (c < 24) ? hem_emb[hem[i] * 24 + c]
                     : subnet_emb[subnet[i] * 24 + (c - 24)];
  }
  __syncthreads();
  if (tid < 48) {
    float s = 0.f;
    for (int i = 0; i < 96; i++) s += fmaxf(xs[i * 96 + tid] + al[i * 48 + tid], 0.f);
    s1[tid] = s;
  }
  for (int o = tid; o < 96 * 48; o += 256) {
    int j = o / 48, c = o % 48;
    float av = al[j * 48 + c];
    float s = 0.f;
    for (int i = 0; i < 96; i++) s += fmaxf(xs[i * 96 + 48 + c] + av, 0.f);
    s2[o] = s;
  }
  __syncthreads();
  for (int o = tid; o < 96 * 96; o += 256) {
    int j = o / 96, d = o % 96;
    float aggv = (d < 48) ? s1[d] : s2[j * 48 + (d - 48)];
    gin[t * 9216 + o] = xs[o] + aggv;
  }
}

// ---------------------------------------------------------------------------
// K2a: fused 2-layer GINE MLP + residual over 64-row tiles. H may alias gin.
// ---------------------------------------------------------------------------
__global__ __launch_bounds__(256) void k2_mlp(
    const float* __restrict__ gin, const float* __restrict__ input,
    const float* __restrict__ W1, const float* __restrict__ b1,
    const float* __restrict__ W2, const float* __restrict__ b2,
    float* __restrict__ H) {
  int r0 = blockIdx.x * 64;
  __shared__ float As[64][97];
  __shared__ float Bs[96][96];
  __shared__ float Hd[64][97];
  int tid = threadIdx.x;
  int tx = tid & 15, ty = tid >> 4;
  int c0 = tx * 6;
  int rb = ty * 4;

  for (int o = tid; o < 64 * 96; o += 256) As[o / 96][o % 96] = gin[(size_t)r0 * 96 + o];
  for (int o = tid; o < 96 * 96; o += 256) ((float*)Bs)[o] = W1[o];
  __syncthreads();

  float acc[4][6];
#pragma unroll
  for (int i = 0; i < 4; i++)
#pragma unroll
    for (int j = 0; j < 6; j++) acc[i][j] = b1[c0 + j];

#pragma unroll 4
  for (int k = 0; k < 96; k++) {
    float a0 = As[rb + 0][k], a1 = As[rb + 1][k], a2 = As[rb + 2][k], a3 = As[rb + 3][k];
    float b[6];
#pragma unroll
    for (int j = 0; j < 6; j++) b[j] = Bs[k][c0 + j];
#pragma unroll
    for (int j = 0; j < 6; j++) {
      acc[0][j] += a0 * b[j];
      acc[1][j] += a1 * b[j];
      acc[2][j] += a2 * b[j];
      acc[3][j] += a3 * b[j];
    }
  }
#pragma unroll
  for (int i = 0; i < 4; i++)
#pragma unroll
    for (int j = 0; j < 6; j++) Hd[rb + i][c0 + j] = fmaxf(acc[i][j], 0.f);
  __syncthreads();
  for (int o = tid; o < 96 * 96; o += 256) ((float*)Bs)[o] = W2[o];
#pragma unroll
  for (int i = 0; i < 4; i++)
#pragma unroll
    for (int j = 0; j < 6; j++) acc[i][j] = b2[c0 + j];
  __syncthreads();

#pragma unroll 4
  for (int k = 0; k < 96; k++) {
    float a0 = Hd[rb + 0][k], a1 = Hd[rb + 1][k], a2 = Hd[rb + 2][k], a3 = Hd[rb + 3][k];
    float b[6];
#pragma unroll
    for (int j = 0; j < 6; j++) b[j] = Bs[k][c0 + j];
#pragma unroll
    for (int j = 0; j < 6; j++) {
      acc[0][j] += a0 * b[j];
      acc[1][j] += a1 * b[j];
      acc[2][j] += a2 * b[j];
      acc[3][j] += a3 * b[j];
    }
  }
#pragma unroll
  for (int i = 0; i < 4; i++) {
    int r = r0 + rb + i;
    int t = r / 96, jn = r % 96;
    const float* resr = input + (size_t)jn * TN + t * 96 + c0;
#pragma unroll
    for (int j = 0; j < 6; j++)
      H[(size_t)r * 96 + c0 + j] = acc[i][j] + resr[j];
  }
}

// ---------------------------------------------------------------------------
// K2b: node-batchnorm per t, write z in [b][l][d] layout (fp32)
// ---------------------------------------------------------------------------
__global__ __launch_bounds__(256) void k2_bn(
    const float* __restrict__ H, const float* __restrict__ bn_w,
    const float* __restrict__ bn_b, float* __restrict__ z) {
  int t = blockIdx.x;
  __shared__ float h[96 * 96];
  __shared__ float mu[96], rs[96];
  int tid = threadIdx.x;

  for (int o = tid; o < 9216; o += 256) h[o] = H[(size_t)t * 9216 + o];
  __syncthreads();
  if (tid < 96) {
    float m = 0.f;
    for (int j = 0; j < 96; j++) m += h[j * 96 + tid];
    m *= (1.f / 96.f);
    float v = 0.f;
    for (int j = 0; j < 96; j++) { float dd = h[j * 96 + tid] - m; v += dd * dd; }
    v *= (1.f / 96.f);
    mu[tid] = m;
    rs[tid] = rsqrtf(v + BN_EPS);
  }
  __syncthreads();
  for (int o = tid; o < 9216; o += 256) {
    int j = o / 96, d = o % 96;
    z[(size_t)j * TN + t * 96 + d] = (h[o] - mu[d]) * rs[d] * bn_w[d] + bn_b[d];
  }
}

// ---------------------------------------------------------------------------
// K_convW: in_proj fp32 [96][1158] -> transposed bf16 WT [1158][96]
// ---------------------------------------------------------------------------
__global__ __launch_bounds__(256) void k_convW(
    const float* __restrict__ ip, unsigned short* __restrict__ WT) {
  int idx = blockIdx.x * 256 + threadIdx.x;
  if (idx < 96 * D_IN_PROJ) {
    int k = idx / D_IN_PROJ, n = idx - k * D_IN_PROJ;
    WT[(size_t)n * 96 + k] = bf16r(ip[idx]);
  }
}

// ---------------------------------------------------------------------------
// K3: in_proj GEMM via bf16 MFMA: (15360x96)@(96x1158) -> zxbcdt (fp32)
// ---------------------------------------------------------------------------
__global__ __launch_bounds__(256) void k3_mfma(
    const float* __restrict__ Z, const unsigned short* __restrict__ WT,
    float* __restrict__ C) {
  int m0 = blockIdx.x * 128;
  int n0 = blockIdx.y * 64;
  __shared__ unsigned short As[128][104];
  __shared__ unsigned short Bs[64][104];
  int tid = threadIdx.x;
  int lane = tid & 63, w = tid >> 6;

  for (int o = tid; o < 128 * 24; o += 256) {
    int r = o / 24, c4 = (o % 24) * 4;
    float4 v = *(const float4*)&Z[(size_t)(m0 + r) * 96 + c4];
    unsigned int p0 = pack_bf2(v.x, v.y);
    unsigned int p1 = pack_bf2(v.z, v.w);
    *(uint2*)&As[r][c4] = make_uint2(p0, p1);
  }
  for (int o = tid; o < 64 * 12; o += 256) {
    int nr = o / 12, seg = (o % 12) * 8;
    int n = n0 + nr;
    short8 v = {};
    if (n < D_IN_PROJ) v = *(const short8*)&WT[(size_t)n * 96 + seg];
    *(short8*)&Bs[nr][seg] = v;
  }
  __syncthreads();

  int q = lane >> 4, r16 = lane & 15;
  int wm = w * 32;
  f32x4 acc[2][4] = {};

#pragma unroll
  for (int ks = 0; ks < 3; ks++) {
    int k0 = ks * 32 + q * 8;
    short8 a0 = *(const short8*)&As[wm + r16][k0];
    short8 a1 = *(const short8*)&As[wm + 16 + r16][k0];
    short8 b0 = *(const short8*)&Bs[r16][k0];
    short8 b1 = *(const short8*)&Bs[16 + r16][k0];
    short8 b2 = *(const short8*)&Bs[32 + r16][k0];
    short8 b3 = *(const short8*)&Bs[48 + r16][k0];
    acc[0][0] = __builtin_amdgcn_mfma_f32_16x16x32_bf16(a0, b0, acc[0][0], 0, 0, 0);
    acc[0][1] = __builtin_amdgcn_mfma_f32_16x16x32_bf16(a0, b1, acc[0][1], 0, 0, 0);
    acc[0][2] = __builtin_amdgcn_mfma_f32_16x16x32_bf16(a0, b2, acc[0][2], 0, 0, 0);
    acc[0][3] = __builtin_amdgcn_mfma_f32_16x16x32_bf16(a0, b3, acc[0][3], 0, 0, 0);
    acc[1][0] = __builtin_amdgcn_mfma_f32_16x16x32_bf16(a1, b0, acc[1][0], 0, 0, 0);
    acc[1][1] = __builtin_amdgcn_mfma_f32_16x16x32_bf16(a1, b1, acc[1][1], 0, 0, 0);
    acc[1][2] = __builtin_amdgcn_mfma_f32_16x16x32_bf16(a1, b2, acc[1][2], 0, 0, 0);
    acc[1][3] = __builtin_amdgcn_mfma_f32_16x16x32_bf16(a1, b3, acc[1][3], 0, 0, 0);
  }

#pragma unroll
  for (int mf = 0; mf < 2; mf++) {
#pragma unroll
    for (int nf = 0; nf < 4; nf++) {
      int col = n0 + nf * 16 + r16;
      if (col < D_IN_PROJ) {
        int rowb = m0 + wm + mf * 16 + q * 4;
#pragma unroll
        for (int reg = 0; reg < 4; reg++)
          C[(size_t)(rowb + reg) * D_IN_PROJ + col] = acc[mf][nf][reg];
      }
    }
  }
}

// ---------------------------------------------------------------------------
// K5: fused causal-conv + silu + softplus(dt) + SSM scan. Block per (b,h).
// Async-STAGE pipeline: regs hold chunk ch (loaded last iteration); write
// them to LDS, immediately issue chunk ch+1's loads (latency hides under
// conv+scan), 2 barriers per chunk. History rows re-loaded from global
// (rows t0-3..t0+CHUNK-1) instead of LDS shifting.
// ---------------------------------------------------------------------------
#define CHUNK 32
#define NCH 5            // 160 / CHUNK
#define NV ((CHUNK + 3) * 40)  // float4 vectors per chunk = 1400

__global__ __launch_bounds__(256) void k5_scan(
    const float* __restrict__ zx, const float* __restrict__ conv_w,
    const float* __restrict__ conv_b, const float* __restrict__ dt_bias,
    const float* __restrict__ A_log, const float* __restrict__ Dparam,
    float* __restrict__ y) {
  int b = blockIdx.x;  // 96
  int h = blockIdx.y;  // 6
  int tid = threadIdx.x;

  __shared__ float raw[CHUNK + 3][160];  // rows t0-3 .. t0+CHUNK-1
  __shared__ float cur[CHUNK][160];      // x[0:32] B[32:96] C[96:160]
  __shared__ float dt_s[CHUNK], dA_s[CHUNK];

  float cw0 = 0, cw1 = 0, cw2 = 0, cw3 = 0, cb = 0;
  if (tid < 160) {
    int c;
    if (tid < 32)       c = h * 32 + tid;
    else if (tid < 96)  c = 192 + h * 64 + (tid - 32);
    else                c = 576 + h * 64 + (tid - 96);
    cw0 = conv_w[c * 4 + 0];
    cw1 = conv_w[c * 4 + 1];
    cw2 = conv_w[c * 4 + 2];
    cw3 = conv_w[c * 4 + 3];
    cb = conv_b[c];
  }
  float Ah = -expf(A_log[h]);
  float Dh = Dparam[h];
  float dtb = dt_bias[h];

  int baseA = 192 + h * 32;
  int baseB = 352 + h * 64;
  int baseC = 672 + h * 64;

  const float* zrow = zx + (size_t)b * 160 * D_IN_PROJ;

  // ---- prefetch chunk 0 into regs ----
  float4 r[6];
  float rdt = 0.f;
#pragma unroll
  for (int i = 0; i < 6; i++) {
    int v = tid + 256 * i;
    if (v < NV) {
      int tt = v / 40, c = (v % 40) * 4;
      int t = tt - 3;
      int col = c + ((c < 32) ? baseA : (c < 96) ? baseB : baseC);
      float4 val = {0.f, 0.f, 0.f, 0.f};
      if (t >= 0) val = *(const float4*)&zrow[(size_t)t * D_IN_PROJ + col];
      r[i] = val;
    }
  }
  if (tid >= 192 && tid < 192 + CHUNK)
    rdt = zrow[(size_t)(tid - 192) * D_IN_PROJ + 1152 + h];

  float s[8];
#pragma unroll
  for (int i = 0; i < 8; i++) s[i] = 0.f;
  int p = tid >> 3, ng = tid & 7;

  for (int ch = 0; ch < NCH; ch++) {
    int t0 = ch * CHUNK;

    // ---- write prefetched regs to LDS ----
#pragma unroll
    for (int i = 0; i < 6; i++) {
      int v = tid + 256 * i;
      if (v < NV) {
        int tt = v / 40, c = (v % 40) * 4;
        *(float4*)&raw[tt][c] = r[i];
      }
    }
    float rdt_use = rdt;

    // ---- issue next chunk's loads (latency hides under conv+scan) ----
    if (ch + 1 < NCH) {
      int t1 = t0 + CHUNK;
#pragma unroll
      for (int i = 0; i < 6; i++) {
        int v = tid + 256 * i;
        if (v < NV) {
          int tt = v / 40, c = (v % 40) * 4;
          int t = t1 - 3 + tt;
          int col = c + ((c < 32) ? baseA : (c < 96) ? baseB : baseC);
          r[i] = *(const float4*)&zrow[(size_t)t * D_IN_PROJ + col];
        }
      }
      if (tid >= 192 && tid < 192 + CHUNK)
        rdt = zrow[(size_t)(t1 + tid - 192) * D_IN_PROJ + 1152 + h];
    }

    // dt/dA in regs (no LDS dependency)
    float dtv_r = 0.f, dAv_r = 0.f;
    if (tid >= 192 && tid < 192 + CHUNK) {
      dtv_r = softplusf(rdt_use + dtb);
      dAv_r = expf(dtv_r * Ah);
    }

    __syncthreads();  // raw visible; previous scan done with cur/dt_s

    if (tid < 160) {
#pragma unroll 8
      for (int tt = 0; tt < CHUNK; tt++) {
        float acc = cb + raw[tt + 0][tid] * cw0 + raw[tt + 1][tid] * cw1 +
                    raw[tt + 2][tid] * cw2 + raw[tt + 3][tid] * cw3;
        cur[tt][tid] = siluf(acc);
      }
    } else if (tid >= 192 && tid < 192 + CHUNK) {
      dt_s[tid - 192] = dtv_r;
      dA_s[tid - 192] = dAv_r;
    }
    __syncthreads();  // cur, dt_s ready

    // ---- scan: CHUNK serial steps, LDS reads only, no barriers ----
    for (int tt = 0; tt < CHUNK; tt++) {
      float dtv = dt_s[tt], dAv = dA_s[tt];
      float xv = cur[tt][p];
      float dtx = dtv * xv;
      const float4* Bp = (const float4*)&cur[tt][32 + ng * 8];
      const float4* Cp = (const float4*)&cur[tt][96 + ng * 8];
      float4 b0 = Bp[0], b1 = Bp[1];
      float4 c0 = Cp[0], c1 = Cp[1];
      float part;
      s[0] = s[0] * dAv + dtx * b0.x;
      s[1] = s[1] * dAv + dtx * b0.y;
      s[2] = s[2] * dAv + dtx * b0.z;
      s[3] = s[3] * dAv + dtx * b0.w;
      s[4] = s[4] * dAv + dtx * b1.x;
      s[5] = s[5] * dAv + dtx * b1.y;
      s[6] = s[6] * dAv + dtx * b1.z;
      s[7] = s[7] * dAv + dtx * b1.w;
      part = s[0] * c0.x + s[1] * c0.y + s[2] * c0.z + s[3] * c0.w +
             s[4] * c1.x + s[5] * c1.y + s[6] * c1.z + s[7] * c1.w;
      part += __shfl_xor(part, 1);
      part += __shfl_xor(part, 2);
      part += __shfl_xor(part, 4);
      if (ng == 0)
        y[((size_t)(b * 160 + t0 + tt)) * D_INNER + h * 32 + p] = part + Dh * xv;
    }
  }
}

// ---------------------------------------------------------------------------
// K6: gated RMSNorm + out_proj + partial time-mean. Block per (b, chunk of 20 t).
// ---------------------------------------------------------------------------
__global__ __launch_bounds__(256) void k6_head(
    const float* __restrict__ y, const float* __restrict__ zx,
    const float* __restrict__ norm_w, const float* __restrict__ out_proj,
    float* __restrict__ e_part) {
  int b = blockIdx.x;
  int ch = blockIdx.y;
  int tid = threadIdx.x;
  __shared__ float yn[192];
  __shared__ float eacc[2][96];
  __shared__ float rfac;
  float ereg = 0.f;

  for (int tt = 0; tt < 20; tt++) {
    int t = ch * 20 + tt;
    size_t row = (size_t)(b * 160 + t);
    if (tid < 192) {
      float yv = y[row * D_INNER + tid];
      float zg = zx[row * D_IN_PROJ + tid];
      yn[tid] = yv * siluf(zg);
    }
    __syncthreads();
    if (tid < 64) {
      float v0 = yn[tid], v1 = yn[tid + 64], v2 = yn[tid + 128];
      float ss = v0 * v0 + v1 * v1 + v2 * v2;
      ss += __shfl_xor(ss, 1);
      ss += __shfl_xor(ss, 2);
      ss += __shfl_xor(ss, 4);
      ss += __shfl_xor(ss, 8);
      ss += __shfl_xor(ss, 16);
      ss += __shfl_xor(ss, 32);
      if (tid == 0) rfac = rsqrtf(ss * (1.f / 192.f) + RMS_EPS);
    }
    __syncthreads();
    if (tid < 192) yn[tid] = yn[tid] * rfac * norm_w[tid];
    __syncthreads();
    if (tid < 192) {
      int d = tid % 96, half = tid / 96;
      float acc = 0.f;
      int k0 = half * 96;
      for (int k = k0; k < k0 + 96; k++) acc += yn[k] * out_proj[(size_t)k * 96 + d];
      eacc[half][d] = acc;
    }
    __syncthreads();
    if (tid < 96) ereg += eacc[0][tid] + eacc[1][tid];
    __syncthreads();
  }
  if (tid < 96) e_part[(size_t)ch * 9216 + b * 96 + tid] = ereg;
}

// ---------------------------------------------------------------------------
// K7: reduce chunks, final heads: x1, mu, sigma
// ---------------------------------------------------------------------------
__global__ __launch_bounds__(128) void k7_out(
    const float* __restrict__ e_part, const float* __restrict__ fcw,
    const float* __restrict__ fcb, const float* __restrict__ mu_w,
    const float* __restrict__ mu_b, const float* __restrict__ sg_w,
    const float* __restrict__ sg_b, float* __restrict__ out) {
  int b = blockIdx.x;
  int tid = threadIdx.x;
  __shared__ float em[96];
  __shared__ float x1[96];
  if (tid < 96) {
    float s = 0.f;
    for (int c = 0; c < 8; c++) s += e_part[(size_t)c * 9216 + b * 96 + tid];
    em[tid] = s * (1.f / 160.f);
  }
  __syncthreads();
  if (tid < 96) {
    float acc = fcb[tid];
    for (int k = 0; k < 96; k++) acc += em[k] * fcw[k * 96 + tid];
    float tv = tanhf(acc);
    float ev = (tv > 0.f) ? tv : expm1f(tv);
    x1[tid] = ev;
    out[b * 96 + tid] = ev;
  }
  __syncthreads();
  int j = tid & 63, which = tid >> 6;
  if (which == 0) {
    float acc = mu_b[j];
    for (int k = 0; k < 96; k++) acc += x1[k] * mu_w[k * 64 + j];
    out[9216 + b * 64 + j] = acc;
  } else {
    float acc = sg_b[j];
    for (int k = 0; k < 96; k++) acc += x1[k] * sg_w[k * 64 + j];
    float ev = (acc > 0.f) ? acc : expm1f(acc);
    out[9216 + 6144 + b * 64 + j] = ev + 1.f + 1e-14f;
  }
}

// ---------------------------------------------------------------------------
extern "C" void kernel_launch(void* const* d_in, const int* in_sizes, int n_in,
                              void* d_out, int out_size, void* d_ws,
                              size_t ws_size, hipStream_t stream) {
  const float* input      = (const float*)d_in[0];
  const int*   hem        = (const int*)d_in[1];
  const int*   subnet     = (const int*)d_in[2];
  const float* gine_w1    = (const float*)d_in[3];
  const float* gine_b1    = (const float*)d_in[4];
  const float* gine_w2    = (const float*)d_in[5];
  const float* gine_b2    = (const float*)d_in[6];
  const float* bn_w       = (const float*)d_in[7];
  const float* bn_b       = (const float*)d_in[8];
  const float* hem_emb    = (const float*)d_in[9];
  const float* subnet_emb = (const float*)d_in[10];
  const float* in_proj    = (const float*)d_in[11];
  const float* conv_w     = (const float*)d_in[12];
  const float* conv_b     = (const float*)d_in[13];
  const float* dt_bias    = (const float*)d_in[14];
  const float* A_log      = (const float*)d_in[15];
  const float* Dparam     = (const float*)d_in[16];
  const float* norm_w     = (const float*)d_in[17];
  const float* out_proj   = (const float*)d_in[18];
  const float* out_fc_w   = (const float*)d_in[19];
  const float* out_fc_b   = (const float*)d_in[20];
  const float* mu_w       = (const float*)d_in[21];
  const float* mu_b       = (const float*)d_in[22];
  const float* sigma_w    = (const float*)d_in[23];
  const float* sigma_b    = (const float*)d_in[24];

  float* ws = (float*)d_ws;
  float* gin    = ws;                  // 1,474,560  (k2_mlp output H aliases this)
  float* z      = gin + 1474560;       // 1,474,560
  float* zx     = z + 1474560;         // 17,786,880
  float* y      = zx + 17786880;       // 2,949,120
  float* e_part = y + 2949120;         // 73,728
  // WT (bf16 in_proj^T) aliases the TAIL of y: convW -> k3 -> k5 (overwrites y)
  unsigned short* WT = (unsigned short*)(y + 2893536);
  float* outp = (float*)d_out;

  k_convW<<<435, 256, 0, stream>>>(in_proj, WT);
  k1_agg<<<160, 256, 0, stream>>>(input, hem, subnet, hem_emb, subnet_emb, gin);
  k2_mlp<<<240, 256, 0, stream>>>(gin, input, gine_w1, gine_b1, gine_w2,
                                  gine_b2, /*H=*/gin);
  k2_bn<<<160, 256, 0, stream>>>(gin, bn_w, bn_b, z);
  k3_mfma<<<dim3(120, 19), 256, 0, stream>>>(z, WT, zx);
  k5_scan<<<dim3(96, 6), 256, 0, stream>>>(zx, conv_w, conv_b, dt_bias, A_log,
                                           Dparam, y);
  k6_head<<<dim3(96, 8), 256, 0, stream>>>(y, zx, norm_w, out_proj, e_part);
  k7_out<<<96, 128, 0, stream>>>(e_part, out_fc_w, out_fc_b, mu_w, mu_b,
                                 sigma_w, sigma_b, outp);
}

// Round 6
// 201.387 us; speedup vs baseline: 2.5499x; 1.1549x over previous
//
#include <hip/hip_runtime.h>
#include <hip/hip_bf16.h>
#include <math.h>

// Problem constants
#define NB 96        // batch / nodes
#define TT 160       // sequence length
#define DD 96        // feature dim
#define D_STATE 64
#define D_CONV 4
#define HEADDIM 32
#define NGROUPS 6
#define D_INNER 192
#define NHEADS 6
#define EMB 24
#define DOUT 64
#define D_IN_PROJ 1158
#define CONV_DIM 960
#define TN 15360     // TT*DD = input row stride per node, also rows of z
#define BN_EPS 1e-5f
#define RMS_EPS 1e-5f

typedef __attribute__((ext_vector_type(8))) short short8;
typedef __attribute__((ext_vector_type(4))) float f32x4;

__device__ __forceinline__ float siluf(float x) { return x / (1.f + expf(-x)); }
__device__ __forceinline__ float softplusf(float x) {
    return fmaxf(x, 0.f) + log1pf(expf(-fabsf(x)));
}
__device__ __forceinline__ unsigned short bf16r(float x) {
  union { __hip_bfloat16 h; unsigned short u; } cv;
  cv.h = __float2bfloat16(x);
  return cv.u;
}
__device__ __forceinline__ unsigned int pack_bf2(float a, float b) {
  return (unsigned int)bf16r(a) | ((unsigned int)bf16r(b) << 16);
}

// Workgroup barrier WITHOUT vmcnt drain: LDS-visibility only. Global loads
// issued before this stay in flight (the point of the k5 pipeline).
#define WG_BARRIER_LGKM()                                   \
  do {                                                      \
    asm volatile("s_waitcnt lgkmcnt(0)" ::: "memory");      \
    __builtin_amdgcn_s_barrier();                           \
    asm volatile("" ::: "memory");                          \
    __builtin_amdgcn_sched_barrier(0);                      \
  } while (0)

// ---------------------------------------------------------------------------
// K1: per-t aggregation: a-embeddings, s1, s2, gin = xs + agg
// ---------------------------------------------------------------------------
__global__ __launch_bounds__(256) void k1_agg(
    const float* __restrict__ input, const int* __restrict__ hem,
    const int* __restrict__ subnet, const float* __restrict__ hem_emb,
    const float* __restrict__ subnet_emb, float* __restrict__ gin) {
  int t = blockIdx.x;
  __shared__ float xs[96 * 96];
  __shared__ float al[96 * 48];
  __shared__ float s1[48];
  __shared__ float s2[96 * 48];
  int tid = threadIdx.x;

  for (int o = tid; o < 96 * 96; o += 256) {
    int i = o / 96, d = o % 96;
    xs[o] = input[i * TN + t * 96 + d];
  }
  for (int o = tid; o < 96 * 48; o += 256) {
    int i = o / 48, c = o % 48;
    al[o] = (c < 24) ? hem_emb[hem[i] * 24 + c]
                     : subnet_emb[subnet[i] * 24 + (c - 24)];
  }
  __syncthreads();
  if (tid < 48) {
    float s = 0.f;
    for (int i = 0; i < 96; i++) s += fmaxf(xs[i * 96 + tid] + al[i * 48 + tid], 0.f);
    s1[tid] = s;
  }
  for (int o = tid; o < 96 * 48; o += 256) {
    int j = o / 48, c = o % 48;
    float av = al[j * 48 + c];
    float s = 0.f;
    for (int i = 0; i < 96; i++) s += fmaxf(xs[i * 96 + 48 + c] + av, 0.f);
    s2[o] = s;
  }
  __syncthreads();
  for (int o = tid; o < 96 * 96; o += 256) {
    int j = o / 96, d = o % 96;
    float aggv = (d < 48) ? s1[d] : s2[j * 48 + (d - 48)];
    gin[t * 9216 + o] = xs[o] + aggv;
  }
}

// ---------------------------------------------------------------------------
// K2a: fused 2-layer GINE MLP + residual over 64-row tiles. H may alias gin.
// ---------------------------------------------------------------------------
__global__ __launch_bounds__(256) void k2_mlp(
    const float* __restrict__ gin, const float* __restrict__ input,
    const float* __restrict__ W1, const float* __restrict__ b1,
    const float* __restrict__ W2, const float* __restrict__ b2,
    float* __restrict__ H) {
  int r0 = blockIdx.x * 64;
  __shared__ float As[64][97];
  __shared__ float Bs[96][96];
  __shared__ float Hd[64][97];
  int tid = threadIdx.x;
  int tx = tid & 15, ty = tid >> 4;
  int c0 = tx * 6;
  int rb = ty * 4;

  for (int o = tid; o < 64 * 96; o += 256) As[o / 96][o % 96] = gin[(size_t)r0 * 96 + o];
  for (int o = tid; o < 96 * 96; o += 256) ((float*)Bs)[o] = W1[o];
  __syncthreads();

  float acc[4][6];
#pragma unroll
  for (int i = 0; i < 4; i++)
#pragma unroll
    for (int j = 0; j < 6; j++) acc[i][j] = b1[c0 + j];

#pragma unroll 4
  for (int k = 0; k < 96; k++) {
    float a0 = As[rb + 0][k], a1 = As[rb + 1][k], a2 = As[rb + 2][k], a3 = As[rb + 3][k];
    float b[6];
#pragma unroll
    for (int j = 0; j < 6; j++) b[j] = Bs[k][c0 + j];
#pragma unroll
    for (int j = 0; j < 6; j++) {
      acc[0][j] += a0 * b[j];
      acc[1][j] += a1 * b[j];
      acc[2][j] += a2 * b[j];
      acc[3][j] += a3 * b[j];
    }
  }
#pragma unroll
  for (int i = 0; i < 4; i++)
#pragma unroll
    for (int j = 0; j < 6; j++) Hd[rb + i][c0 + j] = fmaxf(acc[i][j], 0.f);
  __syncthreads();
  for (int o = tid; o < 96 * 96; o += 256) ((float*)Bs)[o] = W2[o];
#pragma unroll
  for (int i = 0; i < 4; i++)
#pragma unroll
    for (int j = 0; j < 6; j++) acc[i][j] = b2[c0 + j];
  __syncthreads();

#pragma unroll 4
  for (int k = 0; k < 96; k++) {
    float a0 = Hd[rb + 0][k], a1 = Hd[rb + 1][k], a2 = Hd[rb + 2][k], a3 = Hd[rb + 3][k];
    float b[6];
#pragma unroll
    for (int j = 0; j < 6; j++) b[j] = Bs[k][c0 + j];
#pragma unroll
    for (int j = 0; j < 6; j++) {
      acc[0][j] += a0 * b[j];
      acc[1][j] += a1 * b[j];
      acc[2][j] += a2 * b[j];
      acc[3][j] += a3 * b[j];
    }
  }
#pragma unroll
  for (int i = 0; i < 4; i++) {
    int r = r0 + rb + i;
    int t = r / 96, jn = r % 96;
    const float* resr = input + (size_t)jn * TN + t * 96 + c0;
#pragma unroll
    for (int j = 0; j < 6; j++)
      H[(size_t)r * 96 + c0 + j] = acc[i][j] + resr[j];
  }
}

// ---------------------------------------------------------------------------
// K2b: node-batchnorm per t, write z in [b][l][d] layout (fp32)
// ---------------------------------------------------------------------------
__global__ __launch_bounds__(256) void k2_bn(
    const float* __restrict__ H, const float* __restrict__ bn_w,
    const float* __restrict__ bn_b, float* __restrict__ z) {
  int t = blockIdx.x;
  __shared__ float h[96 * 96];
  __shared__ float mu[96], rs[96];
  int tid = threadIdx.x;

  for (int o = tid; o < 9216; o += 256) h[o] = H[(size_t)t * 9216 + o];
  __syncthreads();
  if (tid < 96) {
    float m = 0.f;
    for (int j = 0; j < 96; j++) m += h[j * 96 + tid];
    m *= (1.f / 96.f);
    float v = 0.f;
    for (int j = 0; j < 96; j++) { float dd = h[j * 96 + tid] - m; v += dd * dd; }
    v *= (1.f / 96.f);
    mu[tid] = m;
    rs[tid] = rsqrtf(v + BN_EPS);
  }
  __syncthreads();
  for (int o = tid; o < 9216; o += 256) {
    int j = o / 96, d = o % 96;
    z[(size_t)j * TN + t * 96 + d] = (h[o] - mu[d]) * rs[d] * bn_w[d] + bn_b[d];
  }
}

// ---------------------------------------------------------------------------
// K_convW: in_proj fp32 [96][1158] -> transposed bf16 WT [1158][96]
// ---------------------------------------------------------------------------
__global__ __launch_bounds__(256) void k_convW(
    const float* __restrict__ ip, unsigned short* __restrict__ WT) {
  int idx = blockIdx.x * 256 + threadIdx.x;
  if (idx < 96 * D_IN_PROJ) {
    int k = idx / D_IN_PROJ, n = idx - k * D_IN_PROJ;
    WT[(size_t)n * 96 + k] = bf16r(ip[idx]);
  }
}

// ---------------------------------------------------------------------------
// K3: in_proj GEMM via bf16 MFMA: (15360x96)@(96x1158) -> zxbcdt (fp32)
// ---------------------------------------------------------------------------
__global__ __launch_bounds__(256) void k3_mfma(
    const float* __restrict__ Z, const unsigned short* __restrict__ WT,
    float* __restrict__ C) {
  int m0 = blockIdx.x * 128;
  int n0 = blockIdx.y * 64;
  __shared__ unsigned short As[128][104];
  __shared__ unsigned short Bs[64][104];
  int tid = threadIdx.x;
  int lane = tid & 63, w = tid >> 6;

  for (int o = tid; o < 128 * 24; o += 256) {
    int r = o / 24, c4 = (o % 24) * 4;
    float4 v = *(const float4*)&Z[(size_t)(m0 + r) * 96 + c4];
    unsigned int p0 = pack_bf2(v.x, v.y);
    unsigned int p1 = pack_bf2(v.z, v.w);
    *(uint2*)&As[r][c4] = make_uint2(p0, p1);
  }
  for (int o = tid; o < 64 * 12; o += 256) {
    int nr = o / 12, seg = (o % 12) * 8;
    int n = n0 + nr;
    short8 v = {};
    if (n < D_IN_PROJ) v = *(const short8*)&WT[(size_t)n * 96 + seg];
    *(short8*)&Bs[nr][seg] = v;
  }
  __syncthreads();

  int q = lane >> 4, r16 = lane & 15;
  int wm = w * 32;
  f32x4 acc[2][4] = {};

#pragma unroll
  for (int ks = 0; ks < 3; ks++) {
    int k0 = ks * 32 + q * 8;
    short8 a0 = *(const short8*)&As[wm + r16][k0];
    short8 a1 = *(const short8*)&As[wm + 16 + r16][k0];
    short8 b0 = *(const short8*)&Bs[r16][k0];
    short8 b1 = *(const short8*)&Bs[16 + r16][k0];
    short8 b2 = *(const short8*)&Bs[32 + r16][k0];
    short8 b3 = *(const short8*)&Bs[48 + r16][k0];
    acc[0][0] = __builtin_amdgcn_mfma_f32_16x16x32_bf16(a0, b0, acc[0][0], 0, 0, 0);
    acc[0][1] = __builtin_amdgcn_mfma_f32_16x16x32_bf16(a0, b1, acc[0][1], 0, 0, 0);
    acc[0][2] = __builtin_amdgcn_mfma_f32_16x16x32_bf16(a0, b2, acc[0][2], 0, 0, 0);
    acc[0][3] = __builtin_amdgcn_mfma_f32_16x16x32_bf16(a0, b3, acc[0][3], 0, 0, 0);
    acc[1][0] = __builtin_amdgcn_mfma_f32_16x16x32_bf16(a1, b0, acc[1][0], 0, 0, 0);
    acc[1][1] = __builtin_amdgcn_mfma_f32_16x16x32_bf16(a1, b1, acc[1][1], 0, 0, 0);
    acc[1][2] = __builtin_amdgcn_mfma_f32_16x16x32_bf16(a1, b2, acc[1][2], 0, 0, 0);
    acc[1][3] = __builtin_amdgcn_mfma_f32_16x16x32_bf16(a1, b3, acc[1][3], 0, 0, 0);
  }

#pragma unroll
  for (int mf = 0; mf < 2; mf++) {
#pragma unroll
    for (int nf = 0; nf < 4; nf++) {
      int col = n0 + nf * 16 + r16;
      if (col < D_IN_PROJ) {
        int rowb = m0 + wm + mf * 16 + q * 4;
#pragma unroll
        for (int reg = 0; reg < 4; reg++)
          C[(size_t)(rowb + reg) * D_IN_PROJ + col] = acc[mf][nf][reg];
      }
    }
  }
}

// ---------------------------------------------------------------------------
// K5: fused causal-conv + silu + softplus(dt) + SSM scan. Block per (b,h).
// Pipeline with LGKM-only barriers: prefetched global loads stay in flight
// across the whole conv+scan phase (no vmcnt(0) drain at the barrier).
// ---------------------------------------------------------------------------
#define CHUNK 32
#define NCH 5            // 160 / CHUNK
#define NV ((CHUNK + 3) * 40)  // float4 vectors per chunk = 1400

__global__ __launch_bounds__(256) void k5_scan(
    const float* __restrict__ zx, const float* __restrict__ conv_w,
    const float* __restrict__ conv_b, const float* __restrict__ dt_bias,
    const float* __restrict__ A_log, const float* __restrict__ Dparam,
    float* __restrict__ y) {
  int b = blockIdx.x;  // 96
  int h = blockIdx.y;  // 6
  int tid = threadIdx.x;

  __shared__ float raw[CHUNK + 3][160];  // rows t0-3 .. t0+CHUNK-1
  __shared__ float cur[CHUNK][160];      // x[0:32] B[32:96] C[96:160]
  __shared__ float dt_s[CHUNK], dA_s[CHUNK];

  float cw0 = 0, cw1 = 0, cw2 = 0, cw3 = 0, cb = 0;
  if (tid < 160) {
    int c;
    if (tid < 32)       c = h * 32 + tid;
    else if (tid < 96)  c = 192 + h * 64 + (tid - 32);
    else                c = 576 + h * 64 + (tid - 96);
    cw0 = conv_w[c * 4 + 0];
    cw1 = conv_w[c * 4 + 1];
    cw2 = conv_w[c * 4 + 2];
    cw3 = conv_w[c * 4 + 3];
    cb = conv_b[c];
  }
  float Ah = -expf(A_log[h]);
  float Dh = Dparam[h];
  float dtb = dt_bias[h];

  int baseA = 192 + h * 32;
  int baseB = 352 + h * 64;
  int baseC = 672 + h * 64;

  const float* zrow = zx + (size_t)b * 160 * D_IN_PROJ;

  // ---- prefetch chunk 0 into regs ----
  float4 r[6];
  float rdt = 0.f;
#pragma unroll
  for (int i = 0; i < 6; i++) {
    int v = tid + 256 * i;
    if (v < NV) {
      int tt = v / 40, c = (v % 40) * 4;
      int t = tt - 3;
      int col = c + ((c < 32) ? baseA : (c < 96) ? baseB : baseC);
      float4 val = {0.f, 0.f, 0.f, 0.f};
      if (t >= 0) val = *(const float4*)&zrow[(size_t)t * D_IN_PROJ + col];
      r[i] = val;
    }
  }
  if (tid >= 192 && tid < 192 + CHUNK)
    rdt = zrow[(size_t)(tid - 192) * D_IN_PROJ + 1152 + h];

  float s[8];
#pragma unroll
  for (int i = 0; i < 8; i++) s[i] = 0.f;
  int p = tid >> 3, ng = tid & 7;

  for (int ch = 0; ch < NCH; ch++) {
    int t0 = ch * CHUNK;

    // ---- write prefetched regs to LDS (compiler waits vmcnt on r uses) ----
#pragma unroll
    for (int i = 0; i < 6; i++) {
      int v = tid + 256 * i;
      if (v < NV) {
        int tt = v / 40, c = (v % 40) * 4;
        *(float4*)&raw[tt][c] = r[i];
      }
    }
    float rdt_use = rdt;

    // ---- issue next chunk's loads; they stay in flight across barriers ----
    if (ch + 1 < NCH) {
      int t1 = t0 + CHUNK;
#pragma unroll
      for (int i = 0; i < 6; i++) {
        int v = tid + 256 * i;
        if (v < NV) {
          int tt = v / 40, c = (v % 40) * 4;
          int t = t1 - 3 + tt;
          int col = c + ((c < 32) ? baseA : (c < 96) ? baseB : baseC);
          r[i] = *(const float4*)&zrow[(size_t)t * D_IN_PROJ + col];
        }
      }
      if (tid >= 192 && tid < 192 + CHUNK)
        rdt = zrow[(size_t)(t1 + tid - 192) * D_IN_PROJ + 1152 + h];
    }

    // dt/dA in regs (no LDS dependency)
    float dtv_r = 0.f, dAv_r = 0.f;
    if (tid >= 192 && tid < 192 + CHUNK) {
      dtv_r = softplusf(rdt_use + dtb);
      dAv_r = expf(dtv_r * Ah);
    }

    WG_BARRIER_LGKM();  // raw visible; previous scan done with cur/dt_s

    if (tid < 160) {
#pragma unroll 8
      for (int tt = 0; tt < CHUNK; tt++) {
        float acc = cb + raw[tt + 0][tid] * cw0 + raw[tt + 1][tid] * cw1 +
                    raw[tt + 2][tid] * cw2 + raw[tt + 3][tid] * cw3;
        cur[tt][tid] = siluf(acc);
      }
    } else if (tid >= 192 && tid < 192 + CHUNK) {
      dt_s[tid - 192] = dtv_r;
      dA_s[tid - 192] = dAv_r;
    }

    WG_BARRIER_LGKM();  // cur, dt_s ready

    // ---- scan: CHUNK serial steps, software-pipelined LDS reads ----
    float4 nb0 = *(const float4*)&cur[0][32 + ng * 8];
    float4 nb1 = *(const float4*)&cur[0][32 + ng * 8 + 4];
    float4 nc0 = *(const float4*)&cur[0][96 + ng * 8];
    float4 nc1 = *(const float4*)&cur[0][96 + ng * 8 + 4];
    float xvn = cur[0][p], dtn = dt_s[0], dAn = dA_s[0];
    for (int tt = 0; tt < CHUNK; tt++) {
      float4 b0 = nb0, b1 = nb1, c0 = nc0, c1 = nc1;
      float xv = xvn, dtv = dtn, dAv = dAn;
      if (tt + 1 < CHUNK) {
        nb0 = *(const float4*)&cur[tt + 1][32 + ng * 8];
        nb1 = *(const float4*)&cur[tt + 1][32 + ng * 8 + 4];
        nc0 = *(const float4*)&cur[tt + 1][96 + ng * 8];
        nc1 = *(const float4*)&cur[tt + 1][96 + ng * 8 + 4];
        xvn = cur[tt + 1][p];
        dtn = dt_s[tt + 1];
        dAn = dA_s[tt + 1];
      }
      float dtx = dtv * xv;
      float part;
      s[0] = s[0] * dAv + dtx * b0.x;
      s[1] = s[1] * dAv + dtx * b0.y;
      s[2] = s[2] * dAv + dtx * b0.z;
      s[3] = s[3] * dAv + dtx * b0.w;
      s[4] = s[4] * dAv + dtx * b1.x;
      s[5] = s[5] * dAv + dtx * b1.y;
      s[6] = s[6] * dAv + dtx * b1.z;
      s[7] = s[7] * dAv + dtx * b1.w;
      part = s[0] * c0.x + s[1] * c0.y + s[2] * c0.z + s[3] * c0.w +
             s[4] * c1.x + s[5] * c1.y + s[6] * c1.z + s[7] * c1.w;
      part += __shfl_xor(part, 1);
      part += __shfl_xor(part, 2);
      part += __shfl_xor(part, 4);
      if (ng == 0)
        y[((size_t)(b * 160 + t0 + tt)) * D_INNER + h * 32 + p] = part + Dh * xv;
    }
  }
}

// ---------------------------------------------------------------------------
// K6: gated RMSNorm + out_proj + partial time-mean. Block per (b, 16-t tile).
// Fully parallel: 3 barriers total (was 6 per timestep).
// ---------------------------------------------------------------------------
#define K6T 16

__global__ __launch_bounds__(256) void k6_head(
    const float* __restrict__ y, const float* __restrict__ zx,
    const float* __restrict__ norm_w, const float* __restrict__ out_proj,
    float* __restrict__ e_part) {
  int b = blockIdx.x;
  int ch = blockIdx.y;  // 10 chunks x 16 timesteps
  int tid = threadIdx.x;
  __shared__ float g[K6T][200];   // gated (later normed) values
  __shared__ float rf[K6T];
  __shared__ float nw[192];
  __shared__ float ep[K6T][97];   // per-t GEMM outputs (97: bank-conflict-free)
  int t0 = ch * K6T;

  if (tid < 192) nw[tid] = norm_w[tid];

  // phase 1: g = y * silu(zg)   (16 rows x 48 float4 = 768 vectors)
  for (int v = tid; v < K6T * 48; v += 256) {
    int tt = v / 48, c4 = (v % 48) * 4;
    size_t row = (size_t)(b * 160 + t0 + tt);
    float4 yv = *(const float4*)&y[row * D_INNER + c4];
    float4 zg = *(const float4*)&zx[row * D_IN_PROJ + c4];
    float4 gv;
    gv.x = yv.x * siluf(zg.x);
    gv.y = yv.y * siluf(zg.y);
    gv.z = yv.z * siluf(zg.z);
    gv.w = yv.w * siluf(zg.w);
    *(float4*)&g[tt][c4] = gv;
  }
  __syncthreads();

  // phase 2: rms factor per t (16 lanes per row)
  {
    int tt = tid >> 4, l = tid & 15;
    float ss = 0.f;
    for (int k = l; k < 192; k += 16) {
      float v = g[tt][k];
      ss += v * v;
    }
    ss += __shfl_xor(ss, 1);
    ss += __shfl_xor(ss, 2);
    ss += __shfl_xor(ss, 4);
    ss += __shfl_xor(ss, 8);
    if (l == 0) rf[tt] = rsqrtf(ss * (1.f / 192.f) + RMS_EPS);
  }
  __syncthreads();

  // phase 3: scale by rf * norm_w (in place)
  for (int v = tid; v < K6T * 48; v += 256) {
    int tt = v / 48, c4 = (v % 48) * 4;
    float rr = rf[tt];
    float4 gv = *(float4*)&g[tt][c4];
    gv.x *= rr * nw[c4 + 0];
    gv.y *= rr * nw[c4 + 1];
    gv.z *= rr * nw[c4 + 2];
    gv.w *= rr * nw[c4 + 3];
    *(float4*)&g[tt][c4] = gv;
  }
  __syncthreads();

  // phase 4: GEMM 16x192 @ 192x96. Active: 192 threads = 16 t x 12 d-groups.
  if (tid < 192) {
    int tt = tid & 15, grp = tid >> 4;  // grp 0..11
    int d0 = grp * 8;
    float acc[8] = {};
    for (int k = 0; k < 192; k++) {
      float gk = g[tt][k];
      float4 w0 = *(const float4*)&out_proj[(size_t)k * 96 + d0];
      float4 w1 = *(const float4*)&out_proj[(size_t)k * 96 + d0 + 4];
      acc[0] += gk * w0.x;
      acc[1] += gk * w0.y;
      acc[2] += gk * w0.z;
      acc[3] += gk * w0.w;
      acc[4] += gk * w1.x;
      acc[5] += gk * w1.y;
      acc[6] += gk * w1.z;
      acc[7] += gk * w1.w;
    }
#pragma unroll
    for (int j = 0; j < 8; j++) ep[tt][d0 + j] = acc[j];
  }
  __syncthreads();

  // phase 5: reduce over the 16 t's, write partial sum
  if (tid < 96) {
    float s = 0.f;
#pragma unroll
    for (int tt = 0; tt < K6T; tt++) s += ep[tt][tid];
    e_part[(size_t)ch * 9216 + b * 96 + tid] = s;
  }
}

// ---------------------------------------------------------------------------
// K7: reduce chunks, final heads: x1, mu, sigma
// ---------------------------------------------------------------------------
__global__ __launch_bounds__(128) void k7_out(
    const float* __restrict__ e_part, const float* __restrict__ fcw,
    const float* __restrict__ fcb, const float* __restrict__ mu_w,
    const float* __restrict__ mu_b, const float* __restrict__ sg_w,
    const float* __restrict__ sg_b, float* __restrict__ out) {
  int b = blockIdx.x;
  int tid = threadIdx.x;
  __shared__ float em[96];
  __shared__ float x1[96];
  if (tid < 96) {
    float s = 0.f;
    for (int c = 0; c < 10; c++) s += e_part[(size_t)c * 9216 + b * 96 + tid];
    em[tid] = s * (1.f / 160.f);
  }
  __syncthreads();
  if (tid < 96) {
    float acc = fcb[tid];
    for (int k = 0; k < 96; k++) acc += em[k] * fcw[k * 96 + tid];
    float tv = tanhf(acc);
    float ev = (tv > 0.f) ? tv : expm1f(tv);
    x1[tid] = ev;
    out[b * 96 + tid] = ev;
  }
  __syncthreads();
  int j = tid & 63, which = tid >> 6;
  if (which == 0) {
    float acc = mu_b[j];
    for (int k = 0; k < 96; k++) acc += x1[k] * mu_w[k * 64 + j];
    out[9216 + b * 64 + j] = acc;
  } else {
    float acc = sg_b[j];
    for (int k = 0; k < 96; k++) acc += x1[k] * sg_w[k * 64 + j];
    float ev = (acc > 0.f) ? acc : expm1f(acc);
    out[9216 + 6144 + b * 64 + j] = ev + 1.f + 1e-14f;
  }
}

// ---------------------------------------------------------------------------
extern "C" void kernel_launch(void* const* d_in, const int* in_sizes, int n_in,
                              void* d_out, int out_size, void* d_ws,
                              size_t ws_size, hipStream_t stream) {
  const float* input      = (const float*)d_in[0];
  const int*   hem        = (const int*)d_in[1];
  const int*   subnet     = (const int*)d_in[2];
  const float* gine_w1    = (const float*)d_in[3];
  const float* gine_b1    = (const float*)d_in[4];
  const float* gine_w2    = (const float*)d_in[5];
  const float* gine_b2    = (const float*)d_in[6];
  const float* bn_w       = (const float*)d_in[7];
  const float* bn_b       = (const float*)d_in[8];
  const float* hem_emb    = (const float*)d_in[9];
  const float* subnet_emb = (const float*)d_in[10];
  const float* in_proj    = (const float*)d_in[11];
  const float* conv_w     = (const float*)d_in[12];
  const float* conv_b     = (const float*)d_in[13];
  const float* dt_bias    = (const float*)d_in[14];
  const float* A_log      = (const float*)d_in[15];
  const float* Dparam     = (const float*)d_in[16];
  const float* norm_w     = (const float*)d_in[17];
  const float* out_proj   = (const float*)d_in[18];
  const float* out_fc_w   = (const float*)d_in[19];
  const float* out_fc_b   = (const float*)d_in[20];
  const float* mu_w       = (const float*)d_in[21];
  const float* mu_b       = (const float*)d_in[22];
  const float* sigma_w    = (const float*)d_in[23];
  const float* sigma_b    = (const float*)d_in[24];

  float* ws = (float*)d_ws;
  float* gin    = ws;                  // 1,474,560  (k2_mlp output H aliases this)
  float* z      = gin + 1474560;       // 1,474,560
  float* zx     = z + 1474560;         // 17,786,880
  float* y      = zx + 17786880;       // 2,949,120
  float* e_part = y + 2949120;         // 92,160 (10 chunks)
  // WT (bf16 in_proj^T) aliases the TAIL of y: convW -> k3 -> k5 (overwrites y)
  unsigned short* WT = (unsigned short*)(y + 2893536);
  float* outp = (float*)d_out;

  k_convW<<<435, 256, 0, stream>>>(in_proj, WT);
  k1_agg<<<160, 256, 0, stream>>>(input, hem, subnet, hem_emb, subnet_emb, gin);
  k2_mlp<<<240, 256, 0, stream>>>(gin, input, gine_w1, gine_b1, gine_w2,
                                  gine_b2, /*H=*/gin);
  k2_bn<<<160, 256, 0, stream>>>(gin, bn_w, bn_b, z);
  k3_mfma<<<dim3(120, 19), 256, 0, stream>>>(z, WT, zx);
  k5_scan<<<dim3(96, 6), 256, 0, stream>>>(zx, conv_w, conv_b, dt_bias, A_log,
                                           Dparam, y);
  k6_head<<<dim3(96, 10), 256, 0, stream>>>(y, zx, norm_w, out_proj, e_part);
  k7_out<<<96, 128, 0, stream>>>(e_part, out_fc_w, out_fc_b, mu_w, mu_b,
                                 sigma_w, sigma_b, outp);
}

// Round 7
// 200.382 us; speedup vs baseline: 2.5626x; 1.0050x over previous
//
#include <hip/hip_runtime.h>
#include <hip/hip_bf16.h>
#include <math.h>

// Problem constants
#define NB 96        // batch / nodes
#define TT 160       // sequence length
#define DD 96        // feature dim
#define D_STATE 64
#define D_CONV 4
#define HEADDIM 32
#define NGROUPS 6
#define D_INNER 192
#define NHEADS 6
#define EMB 24
#define DOUT 64
#define D_IN_PROJ 1158
#define CONV_DIM 960
#define TN 15360     // TT*DD = input row stride per node, also rows of z
#define BN_EPS 1e-5f
#define RMS_EPS 1e-5f

typedef __attribute__((ext_vector_type(8))) short short8;
typedef __attribute__((ext_vector_type(4))) float f32x4;

__device__ __forceinline__ float siluf(float x) { return x / (1.f + expf(-x)); }
__device__ __forceinline__ float softplusf(float x) {
    return fmaxf(x, 0.f) + log1pf(expf(-fabsf(x)));
}
__device__ __forceinline__ unsigned short bf16r(float x) {
  union { __hip_bfloat16 h; unsigned short u; } cv;
  cv.h = __float2bfloat16(x);
  return cv.u;
}
__device__ __forceinline__ unsigned int pack_bf2(float a, float b) {
  return (unsigned int)bf16r(a) | ((unsigned int)bf16r(b) << 16);
}
__device__ __forceinline__ float readlane_f(float v, int l) {
  return __int_as_float(__builtin_amdgcn_readlane(__float_as_int(v), l));
}

// Workgroup barrier WITHOUT vmcnt drain: LDS-visibility only. Global loads
// issued before this stay in flight.
#define WG_BARRIER_LGKM()                                   \
  do {                                                      \
    asm volatile("s_waitcnt lgkmcnt(0)" ::: "memory");      \
    __builtin_amdgcn_s_barrier();                           \
    asm volatile("" ::: "memory");                          \
    __builtin_amdgcn_sched_barrier(0);                      \
  } while (0)

// ---------------------------------------------------------------------------
// K1: per-t aggregation: a-embeddings, s1, s2, gin = xs + agg
// ---------------------------------------------------------------------------
__global__ __launch_bounds__(256) void k1_agg(
    const float* __restrict__ input, const int* __restrict__ hem,
    const int* __restrict__ subnet, const float* __restrict__ hem_emb,
    const float* __restrict__ subnet_emb, float* __restrict__ gin) {
  int t = blockIdx.x;
  __shared__ float xs[96 * 96];
  __shared__ float al[96 * 48];
  __shared__ float s1[48];
  __shared__ float s2[96 * 48];
  int tid = threadIdx.x;

  for (int o = tid; o < 96 * 96; o += 256) {
    int i = o / 96, d = o % 96;
    xs[o] = input[i * TN + t * 96 + d];
  }
  for (int o = tid; o < 96 * 48; o += 256) {
    int i = o / 48, c = o % 48;
    al[o] = (c < 24) ? hem_emb[hem[i] * 24 + c]
                     : subnet_emb[subnet[i] * 24 + (c - 24)];
  }
  __syncthreads();
  if (tid < 48) {
    float s = 0.f;
    for (int i = 0; i < 96; i++) s += fmaxf(xs[i * 96 + tid] + al[i * 48 + tid], 0.f);
    s1[tid] = s;
  }
  for (int o = tid; o < 96 * 48; o += 256) {
    int j = o / 48, c = o % 48;
    float av = al[j * 48 + c];
    float s = 0.f;
    for (int i = 0; i < 96; i++) s += fmaxf(xs[i * 96 + 48 + c] + av, 0.f);
    s2[o] = s;
  }
  __syncthreads();
  for (int o = tid; o < 96 * 96; o += 256) {
    int j = o / 96, d = o % 96;
    float aggv = (d < 48) ? s1[d] : s2[j * 48 + (d - 48)];
    gin[t * 9216 + o] = xs[o] + aggv;
  }
}

// ---------------------------------------------------------------------------
// K2a: fused 2-layer GINE MLP + residual over 64-row tiles. H may alias gin.
// ---------------------------------------------------------------------------
__global__ __launch_bounds__(256) void k2_mlp(
    const float* __restrict__ gin, const float* __restrict__ input,
    const float* __restrict__ W1, const float* __restrict__ b1,
    const float* __restrict__ W2, const float* __restrict__ b2,
    float* __restrict__ H) {
  int r0 = blockIdx.x * 64;
  __shared__ float As[64][97];
  __shared__ float Bs[96][96];
  __shared__ float Hd[64][97];
  int tid = threadIdx.x;
  int tx = tid & 15, ty = tid >> 4;
  int c0 = tx * 6;
  int rb = ty * 4;

  for (int o = tid; o < 64 * 96; o += 256) As[o / 96][o % 96] = gin[(size_t)r0 * 96 + o];
  for (int o = tid; o < 96 * 96; o += 256) ((float*)Bs)[o] = W1[o];
  __syncthreads();

  float acc[4][6];
#pragma unroll
  for (int i = 0; i < 4; i++)
#pragma unroll
    for (int j = 0; j < 6; j++) acc[i][j] = b1[c0 + j];

#pragma unroll 4
  for (int k = 0; k < 96; k++) {
    float a0 = As[rb + 0][k], a1 = As[rb + 1][k], a2 = As[rb + 2][k], a3 = As[rb + 3][k];
    float b[6];
#pragma unroll
    for (int j = 0; j < 6; j++) b[j] = Bs[k][c0 + j];
#pragma unroll
    for (int j = 0; j < 6; j++) {
      acc[0][j] += a0 * b[j];
      acc[1][j] += a1 * b[j];
      acc[2][j] += a2 * b[j];
      acc[3][j] += a3 * b[j];
    }
  }
#pragma unroll
  for (int i = 0; i < 4; i++)
#pragma unroll
    for (int j = 0; j < 6; j++) Hd[rb + i][c0 + j] = fmaxf(acc[i][j], 0.f);
  __syncthreads();
  for (int o = tid; o < 96 * 96; o += 256) ((float*)Bs)[o] = W2[o];
#pragma unroll
  for (int i = 0; i < 4; i++)
#pragma unroll
    for (int j = 0; j < 6; j++) acc[i][j] = b2[c0 + j];
  __syncthreads();

#pragma unroll 4
  for (int k = 0; k < 96; k++) {
    float a0 = Hd[rb + 0][k], a1 = Hd[rb + 1][k], a2 = Hd[rb + 2][k], a3 = Hd[rb + 3][k];
    float b[6];
#pragma unroll
    for (int j = 0; j < 6; j++) b[j] = Bs[k][c0 + j];
#pragma unroll
    for (int j = 0; j < 6; j++) {
      acc[0][j] += a0 * b[j];
      acc[1][j] += a1 * b[j];
      acc[2][j] += a2 * b[j];
      acc[3][j] += a3 * b[j];
    }
  }
#pragma unroll
  for (int i = 0; i < 4; i++) {
    int r = r0 + rb + i;
    int t = r / 96, jn = r % 96;
    const float* resr = input + (size_t)jn * TN + t * 96 + c0;
#pragma unroll
    for (int j = 0; j < 6; j++)
      H[(size_t)r * 96 + c0 + j] = acc[i][j] + resr[j];
  }
}

// ---------------------------------------------------------------------------
// K2b: node-batchnorm per t, write z in [b][l][d] layout (fp32)
// ---------------------------------------------------------------------------
__global__ __launch_bounds__(256) void k2_bn(
    const float* __restrict__ H, const float* __restrict__ bn_w,
    const float* __restrict__ bn_b, float* __restrict__ z) {
  int t = blockIdx.x;
  __shared__ float h[96 * 96];
  __shared__ float mu[96], rs[96];
  int tid = threadIdx.x;

  for (int o = tid; o < 9216; o += 256) h[o] = H[(size_t)t * 9216 + o];
  __syncthreads();
  if (tid < 96) {
    float m = 0.f;
    for (int j = 0; j < 96; j++) m += h[j * 96 + tid];
    m *= (1.f / 96.f);
    float v = 0.f;
    for (int j = 0; j < 96; j++) { float dd = h[j * 96 + tid] - m; v += dd * dd; }
    v *= (1.f / 96.f);
    mu[tid] = m;
    rs[tid] = rsqrtf(v + BN_EPS);
  }
  __syncthreads();
  for (int o = tid; o < 9216; o += 256) {
    int j = o / 96, d = o % 96;
    z[(size_t)j * TN + t * 96 + d] = (h[o] - mu[d]) * rs[d] * bn_w[d] + bn_b[d];
  }
}

// ---------------------------------------------------------------------------
// K_convW: in_proj fp32 [96][1158] -> transposed bf16 WT [1158][96]
// ---------------------------------------------------------------------------
__global__ __launch_bounds__(256) void k_convW(
    const float* __restrict__ ip, unsigned short* __restrict__ WT) {
  int idx = blockIdx.x * 256 + threadIdx.x;
  if (idx < 96 * D_IN_PROJ) {
    int k = idx / D_IN_PROJ, n = idx - k * D_IN_PROJ;
    WT[(size_t)n * 96 + k] = bf16r(ip[idx]);
  }
}

// ---------------------------------------------------------------------------
// K3: in_proj GEMM via bf16 MFMA: (15360x96)@(96x1158) -> zxbcdt (fp32)
// ---------------------------------------------------------------------------
__global__ __launch_bounds__(256) void k3_mfma(
    const float* __restrict__ Z, const unsigned short* __restrict__ WT,
    float* __restrict__ C) {
  int m0 = blockIdx.x * 128;
  int n0 = blockIdx.y * 64;
  __shared__ unsigned short As[128][104];
  __shared__ unsigned short Bs[64][104];
  int tid = threadIdx.x;
  int lane = tid & 63, w = tid >> 6;

  for (int o = tid; o < 128 * 24; o += 256) {
    int r = o / 24, c4 = (o % 24) * 4;
    float4 v = *(const float4*)&Z[(size_t)(m0 + r) * 96 + c4];
    unsigned int p0 = pack_bf2(v.x, v.y);
    unsigned int p1 = pack_bf2(v.z, v.w);
    *(uint2*)&As[r][c4] = make_uint2(p0, p1);
  }
  for (int o = tid; o < 64 * 12; o += 256) {
    int nr = o / 12, seg = (o % 12) * 8;
    int n = n0 + nr;
    short8 v = {};
    if (n < D_IN_PROJ) v = *(const short8*)&WT[(size_t)n * 96 + seg];
    *(short8*)&Bs[nr][seg] = v;
  }
  __syncthreads();

  int q = lane >> 4, r16 = lane & 15;
  int wm = w * 32;
  f32x4 acc[2][4] = {};

#pragma unroll
  for (int ks = 0; ks < 3; ks++) {
    int k0 = ks * 32 + q * 8;
    short8 a0 = *(const short8*)&As[wm + r16][k0];
    short8 a1 = *(const short8*)&As[wm + 16 + r16][k0];
    short8 b0 = *(const short8*)&Bs[r16][k0];
    short8 b1 = *(const short8*)&Bs[16 + r16][k0];
    short8 b2 = *(const short8*)&Bs[32 + r16][k0];
    short8 b3 = *(const short8*)&Bs[48 + r16][k0];
    acc[0][0] = __builtin_amdgcn_mfma_f32_16x16x32_bf16(a0, b0, acc[0][0], 0, 0, 0);
    acc[0][1] = __builtin_amdgcn_mfma_f32_16x16x32_bf16(a0, b1, acc[0][1], 0, 0, 0);
    acc[0][2] = __builtin_amdgcn_mfma_f32_16x16x32_bf16(a0, b2, acc[0][2], 0, 0, 0);
    acc[0][3] = __builtin_amdgcn_mfma_f32_16x16x32_bf16(a0, b3, acc[0][3], 0, 0, 0);
    acc[1][0] = __builtin_amdgcn_mfma_f32_16x16x32_bf16(a1, b0, acc[1][0], 0, 0, 0);
    acc[1][1] = __builtin_amdgcn_mfma_f32_16x16x32_bf16(a1, b1, acc[1][1], 0, 0, 0);
    acc[1][2] = __builtin_amdgcn_mfma_f32_16x16x32_bf16(a1, b2, acc[1][2], 0, 0, 0);
    acc[1][3] = __builtin_amdgcn_mfma_f32_16x16x32_bf16(a1, b3, acc[1][3], 0, 0, 0);
  }

#pragma unroll
  for (int mf = 0; mf < 2; mf++) {
#pragma unroll
    for (int nf = 0; nf < 4; nf++) {
      int col = n0 + nf * 16 + r16;
      if (col < D_IN_PROJ) {
        int rowb = m0 + wm + mf * 16 + q * 4;
#pragma unroll
        for (int reg = 0; reg < 4; reg++)
          C[(size_t)(rowb + reg) * D_IN_PROJ + col] = acc[mf][nf][reg];
      }
    }
  }
}

// ---------------------------------------------------------------------------
// K5: fused causal-conv + silu + softplus(dt) + SSM scan. Block per (b,h).
// v3: DS-instruction diet. Conv = b128 sliding window over 4-channel groups
// (thread = cg 0..39 x tt-octet 0..3); dt/dA fetched once per chunk as a
// packed float2 per lane, then distributed per-step via v_readlane (VALU,
// zero DS). Scan fully unrolled; LGKM-only barriers keep prefetch in flight.
// ---------------------------------------------------------------------------
#define CHUNK 32
#define NCH 5            // 160 / CHUNK
#define NV ((CHUNK + 3) * 40)  // float4 vectors per chunk = 1400

__global__ __launch_bounds__(256) void k5_scan(
    const float* __restrict__ zx, const float* __restrict__ conv_w,
    const float* __restrict__ conv_b, const float* __restrict__ dt_bias,
    const float* __restrict__ A_log, const float* __restrict__ Dparam,
    float* __restrict__ y) {
  int b = blockIdx.x;  // 96
  int h = blockIdx.y;  // 6
  int tid = threadIdx.x;

  __shared__ float raw[CHUNK + 3][160];  // rows t0-3 .. t0+CHUNK-1
  __shared__ float cur[CHUNK][160];      // x[0:32] B[32:96] C[96:160]
  __shared__ float dtA_s[CHUNK * 2];     // interleaved (dt, dA) per step

  // conv setup: thread = (cg, to); channels 4cg..4cg+3, steps 8to..8to+7
  int cg = tid % 40, to = tid / 40;  // valid for tid < 160
  float4 w0 = {}, w1 = {}, w2 = {}, w3 = {}, cbv = {};
  if (tid < 160) {
#pragma unroll
    for (int j = 0; j < 4; j++) {
      int col = cg * 4 + j;
      int c;
      if (col < 32)      c = h * 32 + col;
      else if (col < 96) c = 192 + h * 64 + (col - 32);
      else               c = 576 + h * 64 + (col - 96);
      float4 wt = *(const float4*)&conv_w[c * 4];
      ((float*)&w0)[j] = wt.x;
      ((float*)&w1)[j] = wt.y;
      ((float*)&w2)[j] = wt.z;
      ((float*)&w3)[j] = wt.w;
      ((float*)&cbv)[j] = conv_b[c];
    }
  }
  float Ah = -expf(A_log[h]);
  float Dh = Dparam[h];
  float dtb = dt_bias[h];

  int baseA = 192 + h * 32;
  int baseB = 352 + h * 64;
  int baseC = 672 + h * 64;

  const float* zrow = zx + (size_t)b * 160 * D_IN_PROJ;

  // ---- prefetch chunk 0 into regs ----
  float4 r[6];
  float rdt = 0.f;
#pragma unroll
  for (int i = 0; i < 6; i++) {
    int v = tid + 256 * i;
    if (v < NV) {
      int tt = v / 40, c = (v % 40) * 4;
      int t = tt - 3;
      int col = c + ((c < 32) ? baseA : (c < 96) ? baseB : baseC);
      float4 val = {0.f, 0.f, 0.f, 0.f};
      if (t >= 0) val = *(const float4*)&zrow[(size_t)t * D_IN_PROJ + col];
      r[i] = val;
    }
  }
  if (tid >= 192 && tid < 192 + CHUNK)
    rdt = zrow[(size_t)(tid - 192) * D_IN_PROJ + 1152 + h];

  float s[8];
#pragma unroll
  for (int i = 0; i < 8; i++) s[i] = 0.f;
  int p = tid >> 3, ng = tid & 7;

  for (int ch = 0; ch < NCH; ch++) {
    int t0 = ch * CHUNK;

    // ---- write prefetched regs to LDS ----
#pragma unroll
    for (int i = 0; i < 6; i++) {
      int v = tid + 256 * i;
      if (v < NV) {
        int tt = v / 40, c = (v % 40) * 4;
        *(float4*)&raw[tt][c] = r[i];
      }
    }
    float rdt_use = rdt;

    // ---- issue next chunk's loads; stay in flight across barriers ----
    if (ch + 1 < NCH) {
      int t1 = t0 + CHUNK;
#pragma unroll
      for (int i = 0; i < 6; i++) {
        int v = tid + 256 * i;
        if (v < NV) {
          int tt = v / 40, c = (v % 40) * 4;
          int t = t1 - 3 + tt;
          int col = c + ((c < 32) ? baseA : (c < 96) ? baseB : baseC);
          r[i] = *(const float4*)&zrow[(size_t)t * D_IN_PROJ + col];
        }
      }
      if (tid >= 192 && tid < 192 + CHUNK)
        rdt = zrow[(size_t)(t1 + tid - 192) * D_IN_PROJ + 1152 + h];
    }

    // dt/dA in regs (no LDS dependency)
    float dtv_r = 0.f, dAv_r = 0.f;
    if (tid >= 192 && tid < 192 + CHUNK) {
      dtv_r = softplusf(rdt_use + dtb);
      dAv_r = expf(dtv_r * Ah);
    }

    WG_BARRIER_LGKM();  // raw visible; previous scan done with cur/dtA_s

    // ---- conv + silu: b128 sliding window, 8 steps per thread ----
    if (tid < 160) {
      int c4 = cg * 4;
      int base = to * 8;
      float4 r0 = *(const float4*)&raw[base + 0][c4];
      float4 r1 = *(const float4*)&raw[base + 1][c4];
      float4 r2 = *(const float4*)&raw[base + 2][c4];
#pragma unroll
      for (int i = 0; i < 8; i++) {
        int tt = base + i;
        float4 r3 = *(const float4*)&raw[tt + 3][c4];
        float4 o;
        o.x = cbv.x + r0.x * w0.x + r1.x * w1.x + r2.x * w2.x + r3.x * w3.x;
        o.y = cbv.y + r0.y * w0.y + r1.y * w1.y + r2.y * w2.y + r3.y * w3.y;
        o.z = cbv.z + r0.z * w0.z + r1.z * w1.z + r2.z * w2.z + r3.z * w3.z;
        o.w = cbv.w + r0.w * w0.w + r1.w * w1.w + r2.w * w2.w + r3.w * w3.w;
        o.x = siluf(o.x);
        o.y = siluf(o.y);
        o.z = siluf(o.z);
        o.w = siluf(o.w);
        *(float4*)&cur[tt][c4] = o;
        r0 = r1;
        r1 = r2;
        r2 = r3;
      }
    } else if (tid >= 192 && tid < 192 + CHUNK) {
      int tt = tid - 192;
      dtA_s[2 * tt + 0] = dtv_r;
      dtA_s[2 * tt + 1] = dAv_r;
    }

    WG_BARRIER_LGKM();  // cur, dtA_s ready

    // ---- scan: dt/dA via readlane (lanes 0..31 hold the 32 step-pairs) ----
    float2 myda = *(const float2*)&dtA_s[2 * (tid & 31)];
#pragma unroll
    for (int tt = 0; tt < CHUNK; tt++) {
      float dtv = readlane_f(myda.x, tt);
      float dAv = readlane_f(myda.y, tt);
      float xv = cur[tt][p];
      const float4* Bp = (const float4*)&cur[tt][32 + ng * 8];
      const float4* Cp = (const float4*)&cur[tt][96 + ng * 8];
      float4 b0 = Bp[0], b1 = Bp[1];
      float4 c0 = Cp[0], c1 = Cp[1];
      float dtx = dtv * xv;
      s[0] = s[0] * dAv + dtx * b0.x;
      s[1] = s[1] * dAv + dtx * b0.y;
      s[2] = s[2] * dAv + dtx * b0.z;
      s[3] = s[3] * dAv + dtx * b0.w;
      s[4] = s[4] * dAv + dtx * b1.x;
      s[5] = s[5] * dAv + dtx * b1.y;
      s[6] = s[6] * dAv + dtx * b1.z;
      s[7] = s[7] * dAv + dtx * b1.w;
      float p0 = s[0] * c0.x + s[1] * c0.y;
      float p1 = s[2] * c0.z + s[3] * c0.w;
      float p2 = s[4] * c1.x + s[5] * c1.y;
      float p3 = s[6] * c1.z + s[7] * c1.w;
      float part = (p0 + p1) + (p2 + p3);
      part += __shfl_xor(part, 1);
      part += __shfl_xor(part, 2);
      part += __shfl_xor(part, 4);
      if (ng == 0)
        y[((size_t)(b * 160 + t0 + tt)) * D_INNER + h * 32 + p] = part + Dh * xv;
    }
  }
}

// ---------------------------------------------------------------------------
// K6: gated RMSNorm + out_proj + partial time-mean. Block per (b, 16-t tile).
// ---------------------------------------------------------------------------
#define K6T 16

__global__ __launch_bounds__(256) void k6_head(
    const float* __restrict__ y, const float* __restrict__ zx,
    const float* __restrict__ norm_w, const float* __restrict__ out_proj,
    float* __restrict__ e_part) {
  int b = blockIdx.x;
  int ch = blockIdx.y;  // 10 chunks x 16 timesteps
  int tid = threadIdx.x;
  __shared__ float g[K6T][200];
  __shared__ float rf[K6T];
  __shared__ float nw[192];
  __shared__ float ep[K6T][97];
  int t0 = ch * K6T;

  if (tid < 192) nw[tid] = norm_w[tid];

  for (int v = tid; v < K6T * 48; v += 256) {
    int tt = v / 48, c4 = (v % 48) * 4;
    size_t row = (size_t)(b * 160 + t0 + tt);
    float4 yv = *(const float4*)&y[row * D_INNER + c4];
    float4 zg = *(const float4*)&zx[row * D_IN_PROJ + c4];
    float4 gv;
    gv.x = yv.x * siluf(zg.x);
    gv.y = yv.y * siluf(zg.y);
    gv.z = yv.z * siluf(zg.z);
    gv.w = yv.w * siluf(zg.w);
    *(float4*)&g[tt][c4] = gv;
  }
  __syncthreads();

  {
    int tt = tid >> 4, l = tid & 15;
    float ss = 0.f;
    for (int k = l; k < 192; k += 16) {
      float v = g[tt][k];
      ss += v * v;
    }
    ss += __shfl_xor(ss, 1);
    ss += __shfl_xor(ss, 2);
    ss += __shfl_xor(ss, 4);
    ss += __shfl_xor(ss, 8);
    if (l == 0) rf[tt] = rsqrtf(ss * (1.f / 192.f) + RMS_EPS);
  }
  __syncthreads();

  for (int v = tid; v < K6T * 48; v += 256) {
    int tt = v / 48, c4 = (v % 48) * 4;
    float rr = rf[tt];
    float4 gv = *(float4*)&g[tt][c4];
    gv.x *= rr * nw[c4 + 0];
    gv.y *= rr * nw[c4 + 1];
    gv.z *= rr * nw[c4 + 2];
    gv.w *= rr * nw[c4 + 3];
    *(float4*)&g[tt][c4] = gv;
  }
  __syncthreads();

  if (tid < 192) {
    int tt = tid & 15, grp = tid >> 4;
    int d0 = grp * 8;
    float acc[8] = {};
    for (int k = 0; k < 192; k++) {
      float gk = g[tt][k];
      float4 wv0 = *(const float4*)&out_proj[(size_t)k * 96 + d0];
      float4 wv1 = *(const float4*)&out_proj[(size_t)k * 96 + d0 + 4];
      acc[0] += gk * wv0.x;
      acc[1] += gk * wv0.y;
      acc[2] += gk * wv0.z;
      acc[3] += gk * wv0.w;
      acc[4] += gk * wv1.x;
      acc[5] += gk * wv1.y;
      acc[6] += gk * wv1.z;
      acc[7] += gk * wv1.w;
    }
#pragma unroll
    for (int j = 0; j < 8; j++) ep[tt][d0 + j] = acc[j];
  }
  __syncthreads();

  if (tid < 96) {
    float sum = 0.f;
#pragma unroll
    for (int tt = 0; tt < K6T; tt++) sum += ep[tt][tid];
    e_part[(size_t)ch * 9216 + b * 96 + tid] = sum;
  }
}

// ---------------------------------------------------------------------------
// K7: reduce chunks, final heads: x1, mu, sigma
// ---------------------------------------------------------------------------
__global__ __launch_bounds__(128) void k7_out(
    const float* __restrict__ e_part, const float* __restrict__ fcw,
    const float* __restrict__ fcb, const float* __restrict__ mu_w,
    const float* __restrict__ mu_b, const float* __restrict__ sg_w,
    const float* __restrict__ sg_b, float* __restrict__ out) {
  int b = blockIdx.x;
  int tid = threadIdx.x;
  __shared__ float em[96];
  __shared__ float x1[96];
  if (tid < 96) {
    float s = 0.f;
    for (int c = 0; c < 10; c++) s += e_part[(size_t)c * 9216 + b * 96 + tid];
    em[tid] = s * (1.f / 160.f);
  }
  __syncthreads();
  if (tid < 96) {
    float acc = fcb[tid];
    for (int k = 0; k < 96; k++) acc += em[k] * fcw[k * 96 + tid];
    float tv = tanhf(acc);
    float ev = (tv > 0.f) ? tv : expm1f(tv);
    x1[tid] = ev;
    out[b * 96 + tid] = ev;
  }
  __syncthreads();
  int j = tid & 63, which = tid >> 6;
  if (which == 0) {
    float acc = mu_b[j];
    for (int k = 0; k < 96; k++) acc += x1[k] * mu_w[k * 64 + j];
    out[9216 + b * 64 + j] = acc;
  } else {
    float acc = sg_b[j];
    for (int k = 0; k < 96; k++) acc += x1[k] * sg_w[k * 64 + j];
    float ev = (acc > 0.f) ? acc : expm1f(acc);
    out[9216 + 6144 + b * 64 + j] = ev + 1.f + 1e-14f;
  }
}

// ---------------------------------------------------------------------------
extern "C" void kernel_launch(void* const* d_in, const int* in_sizes, int n_in,
                              void* d_out, int out_size, void* d_ws,
                              size_t ws_size, hipStream_t stream) {
  const float* input      = (const float*)d_in[0];
  const int*   hem        = (const int*)d_in[1];
  const int*   subnet     = (const int*)d_in[2];
  const float* gine_w1    = (const float*)d_in[3];
  const float* gine_b1    = (const float*)d_in[4];
  const float* gine_w2    = (const float*)d_in[5];
  const float* gine_b2    = (const float*)d_in[6];
  const float* bn_w       = (const float*)d_in[7];
  const float* bn_b       = (const float*)d_in[8];
  const float* hem_emb    = (const float*)d_in[9];
  const float* subnet_emb = (const float*)d_in[10];
  const float* in_proj    = (const float*)d_in[11];
  const float* conv_w     = (const float*)d_in[12];
  const float* conv_b     = (const float*)d_in[13];
  const float* dt_bias    = (const float*)d_in[14];
  const float* A_log      = (const float*)d_in[15];
  const float* Dparam     = (const float*)d_in[16];
  const float* norm_w     = (const float*)d_in[17];
  const float* out_proj   = (const float*)d_in[18];
  const float* out_fc_w   = (const float*)d_in[19];
  const float* out_fc_b   = (const float*)d_in[20];
  const float* mu_w       = (const float*)d_in[21];
  const float* mu_b       = (const float*)d_in[22];
  const float* sigma_w    = (const float*)d_in[23];
  const float* sigma_b    = (const float*)d_in[24];

  float* ws = (float*)d_ws;
  float* gin    = ws;                  // 1,474,560  (k2_mlp output H aliases this)
  float* z      = gin + 1474560;       // 1,474,560
  float* zx     = z + 1474560;         // 17,786,880
  float* y      = zx + 17786880;       // 2,949,120
  float* e_part = y + 2949120;         // 92,160 (10 chunks)
  // WT (bf16 in_proj^T) aliases the TAIL of y: convW -> k3 -> k5 (overwrites y)
  unsigned short* WT = (unsigned short*)(y + 2893536);
  float* outp = (float*)d_out;

  k_convW<<<435, 256, 0, stream>>>(in_proj, WT);
  k1_agg<<<160, 256, 0, stream>>>(input, hem, subnet, hem_emb, subnet_emb, gin);
  k2_mlp<<<240, 256, 0, stream>>>(gin, input, gine_w1, gine_b1, gine_w2,
                                  gine_b2, /*H=*/gin);
  k2_bn<<<160, 256, 0, stream>>>(gin, bn_w, bn_b, z);
  k3_mfma<<<dim3(120, 19), 256, 0, stream>>>(z, WT, zx);
  k5_scan<<<dim3(96, 6), 256, 0, stream>>>(zx, conv_w, conv_b, dt_bias, A_log,
                                           Dparam, y);
  k6_head<<<dim3(96, 10), 256, 0, stream>>>(y, zx, norm_w, out_proj, e_part);
  k7_out<<<96, 128, 0, stream>>>(e_part, out_fc_w, out_fc_b, mu_w, mu_b,
                                 sigma_w, sigma_b, outp);
}